// Round 10
// baseline (333.748 us; speedup 1.0000x reference)
//
#include <hip/hip_runtime.h>
#include <math.h>

namespace {

constexpr int kB = 2, kS = 2048, kD = 768, kH = 12, kHD = 64, kF = 128, kBH = kB * kH;

typedef __attribute__((ext_vector_type(8))) short short8;
typedef __attribute__((ext_vector_type(4))) short short4v;
typedef __attribute__((ext_vector_type(4))) float f32x4;

__device__ __forceinline__ ushort f2bf(float x) {
    union { float f; unsigned u; } v; v.f = x;
    return (ushort)((v.u + 0x7fffu + ((v.u >> 16) & 1u)) >> 16);
}
__device__ __forceinline__ float bf2f(ushort u) {
    union { unsigned u; float f; } v; v.u = ((unsigned)u) << 16; return v.f;
}
__device__ __forceinline__ void ntst(float* p, float v) {
    __builtin_nontemporal_store(v, p);
}

__device__ __forceinline__ void gload16(const ushort* g, void* lds) {
    __builtin_amdgcn_global_load_lds(
        (const __attribute__((address_space(1))) void*)g,
        (__attribute__((address_space(3))) void*)lds, 16, 0, 0);
}

// Async-stage 64x64 bf16 tile; LDS rows 128B; swizzle via pre-permuted global src.
__device__ __forceinline__ void gstage64x64(ushort* ldsBase, const ushort* g,
                                            size_t strideElems, int w, int lane) {
    #pragma unroll
    for (int j = 0; j < 2; ++j) {
        const int row = 16 * w + 8 * j + (lane >> 3);
        const int chunk = lane & 7;
        const ushort* gp = g + (size_t)row * strideElems + ((chunk ^ (row & 7)) * 8);
        void* lp = (char*)ldsBase + (16 * w + 8 * j) * 128;
        gload16(gp, lp);
    }
}

// Async-stage 64x128 bf16 tile (rows 256B).
__device__ __forceinline__ void gstage64x128(ushort* ldsBase, const ushort* g,
                                             int w, int lane) {
    #pragma unroll
    for (int j = 0; j < 4; ++j) {
        const int row = 16 * w + 4 * j + (lane >> 4);
        const int chunk = lane & 15;
        const ushort* gp = g + (size_t)row * kF + ((chunk ^ (row & 7)) * 8);
        void* lp = (char*)ldsBase + (16 * w + 4 * j) * 256;
        gload16(gp, lp);
    }
}

// Reg-path stage (outside main loops).
__device__ __forceinline__ void stage64x64(ushort* dst, const ushort* srcRow0,
                                           size_t rowStride, int t) {
    const int row = t >> 2, ce = (t & 3) * 16;
    const ushort* s = srcRow0 + (size_t)row * rowStride + ce;
    uint4 u0 = *(const uint4*)s;
    uint4 u1 = *(const uint4*)(s + 8);
    const int sw = (row & 7) << 4;
    *(uint4*)((char*)dst + row * 128 + ((ce * 2) ^ sw)) = u0;
    *(uint4*)((char*)dst + row * 128 + ((ce * 2 + 16) ^ sw)) = u1;
}

__device__ __forceinline__ void stage64x128(ushort* dst, const ushort* srcRow0, int t) {
    const int row = t >> 2, ce = (t & 3) * 32;
    const ushort* s = srcRow0 + (size_t)row * kF + ce;
    const int sw = (row & 7) << 4;
    #pragma unroll
    for (int u = 0; u < 4; ++u) {
        uint4 x = *(const uint4*)(s + u * 8);
        *(uint4*)((char*)dst + row * 256 + ((ce * 2 + u * 16) ^ sw)) = x;
    }
}

// ---------------- fp32 -> bf16 casts ----------------
__global__ __launch_bounds__(256) void cast_kernel(
    const float* __restrict__ s0, const float* __restrict__ s1,
    const float* __restrict__ s2, const float* __restrict__ s3,
    ushort* __restrict__ d0, ushort* __restrict__ d1,
    ushort* __restrict__ d2, ushort* __restrict__ d3)
{
    const int seg = blockIdx.y;
    const float* src = seg == 0 ? s0 : seg == 1 ? s1 : seg == 2 ? s2 : s3;
    ushort* dst      = seg == 0 ? d0 : seg == 1 ? d1 : seg == 2 ? d2 : d3;
    const int n4 = (seg == 0 ? kB * kS * kD : kD * kD) / 4;
    for (int i = blockIdx.x * 256 + threadIdx.x; i < n4; i += gridDim.x * 256) {
        float4 v = *(const float4*)&src[(size_t)i * 4];
        short4v o;
        o[0] = (short)f2bf(v.x); o[1] = (short)f2bf(v.y);
        o[2] = (short)f2bf(v.z); o[3] = (short)f2bf(v.w);
        *(short4v*)&dst[(size_t)i * 4] = o;
    }
}

// ---------------- QKV projection + fused hedgehog feature map ----------------
__global__ __launch_bounds__(256) void qkv_mfma_kernel(
    const ushort* __restrict__ hb,
    const ushort* __restrict__ Wqb, const ushort* __restrict__ Wkb,
    const ushort* __restrict__ Wvb,
    const float* __restrict__ bq, const float* __restrict__ bk,
    const float* __restrict__ bv,
    const float* __restrict__ Wfq, const float* __restrict__ bfq,
    const float* __restrict__ Wfk, const float* __restrict__ bfk,
    ushort* __restrict__ qd, ushort* __restrict__ kd, ushort* __restrict__ vTd,
    ushort* __restrict__ fqd, ushort* __restrict__ fkd,
    float* __restrict__ part)
{
    const int which = blockIdx.z;
    const ushort* __restrict__ Wb  = which == 0 ? Wqb : which == 1 ? Wkb : Wvb;
    const float* __restrict__ bias = which == 0 ? bq : which == 1 ? bk : bv;

    const int m0 = blockIdx.x * 128;
    const int n0 = blockIdx.y * 64;
    const int t = threadIdx.x, lane = t & 63, w = t >> 6;
    const int g = lane >> 4, ln = lane & 15;

    __shared__ __align__(16) ushort As[128 * 64];
    __shared__ __align__(16) ushort Bs[64 * 64];
    __shared__ __align__(16) ushort Ws[64 * 64];
    __shared__ float zsum[4][128];

    // stage feature-map weight (bf16, swizzled) -- untouched by the main loop
    if (which < 2) {
        const float* __restrict__ Wf = (which == 0) ? Wfq : Wfk;
        const int row = t >> 2, ce = (t & 3) * 16;
        ushort tmp[16];
        #pragma unroll
        for (int c = 0; c < 16; c += 4) {
            float4 u = *(const float4*)&Wf[(size_t)row * 64 + ce + c];
            tmp[c + 0] = f2bf(u.x); tmp[c + 1] = f2bf(u.y);
            tmp[c + 2] = f2bf(u.z); tmp[c + 3] = f2bf(u.w);
        }
        const int sw = (row & 7) << 4;
        *(uint4*)((char*)Ws + row * 128 + ((ce * 2) ^ sw)) = *(uint4*)&tmp[0];
        *(uint4*)((char*)Ws + row * 128 + ((ce * 2 + 16) ^ sw)) = *(uint4*)&tmp[8];
    }

    f32x4 acc[2][4];
    #pragma unroll
    for (int rs = 0; rs < 2; ++rs)
        #pragma unroll
        for (int nt = 0; nt < 4; ++nt) acc[rs][nt] = (f32x4){0.f, 0.f, 0.f, 0.f};

    for (int k0 = 0; k0 < kD; k0 += 64) {
        __syncthreads();
        #pragma unroll
        for (int u = 0; u < 4; ++u) {
            const int ci = u * 256 + t, row = ci >> 3, c = ci & 7;
            uint4 x = *(const uint4*)&hb[(size_t)(m0 + row) * kD + k0 + c * 8];
            *(uint4*)((char*)As + row * 128 + ((c * 16) ^ ((row & 7) << 4))) = x;
        }
        #pragma unroll
        for (int u = 0; u < 2; ++u) {
            const int ci = u * 256 + t, row = ci >> 3, c = ci & 7;
            uint4 x = *(const uint4*)&Wb[(size_t)(n0 + row) * kD + k0 + c * 8];
            *(uint4*)((char*)Bs + row * 128 + ((c * 16) ^ ((row & 7) << 4))) = x;
        }
        __syncthreads();

        short8 a[2][2], b[4][2];
        #pragma unroll
        for (int rs = 0; rs < 2; ++rs) {
            const int row = 32 * w + 16 * rs + ln, sw = (row & 7) << 4;
            #pragma unroll
            for (int kc = 0; kc < 2; ++kc)
                a[rs][kc] = *(const short8*)((const char*)As + row * 128 + ((kc * 64 + g * 16) ^ sw));
        }
        #pragma unroll
        for (int nt = 0; nt < 4; ++nt) {
            const int rk = nt * 16 + ln, sw = (rk & 7) << 4;
            #pragma unroll
            for (int kc = 0; kc < 2; ++kc)
                b[nt][kc] = *(const short8*)((const char*)Bs + rk * 128 + ((kc * 64 + g * 16) ^ sw));
        }
        #pragma unroll
        for (int rs = 0; rs < 2; ++rs)
            #pragma unroll
            for (int nt = 0; nt < 4; ++nt)
                #pragma unroll
                for (int kc = 0; kc < 2; ++kc)
                    acc[rs][nt] = __builtin_amdgcn_mfma_f32_16x16x32_bf16(
                        a[rs][kc], b[nt][kc], acc[rs][nt], 0, 0, 0);
    }

    const int hh = n0 >> 6;
    float bvn[4];
    #pragma unroll
    for (int nt = 0; nt < 4; ++nt) bvn[nt] = bias[n0 + nt * 16 + ln];

    if (which < 2) {
        ushort* __restrict__ dst = (which == 0) ? qd : kd;
        #pragma unroll
        for (int rs = 0; rs < 2; ++rs)
            #pragma unroll
            for (int nt = 0; nt < 4; ++nt)
                #pragma unroll
                for (int r = 0; r < 4; ++r) {
                    const int m = m0 + 32 * w + 16 * rs + g * 4 + r;
                    const int b_ = m >> 11, s_ = m & (kS - 1);
                    dst[((size_t)(b_ * kH + hh) * kS + s_) * kHD + nt * 16 + ln] =
                        f2bf(acc[rs][nt][r] + bvn[nt]);
                }
    } else {
        #pragma unroll
        for (int rs = 0; rs < 2; ++rs)
            #pragma unroll
            for (int nt = 0; nt < 4; ++nt) {
                const int m = m0 + 32 * w + 16 * rs + g * 4;
                const int b_ = m >> 11, s_ = m & (kS - 1);
                const int d = nt * 16 + ln;
                short4v o;
                #pragma unroll
                for (int r = 0; r < 4; ++r) o[r] = (short)f2bf(acc[rs][nt][r] + bvn[nt]);
                *(short4v*)&vTd[((size_t)(b_ * kH + hh) * kHD + d) * kS + s_] = o;
            }
    }

    // ---- fused feature map: f = exp(+/-(x @ Wf^T + bf)) ----
    if (which < 2) {
        __syncthreads();   // all waves finished reading As/Bs
        #pragma unroll
        for (int rs = 0; rs < 2; ++rs)
            #pragma unroll
            for (int nt = 0; nt < 4; ++nt)
                #pragma unroll
                for (int r = 0; r < 4; ++r) {
                    const int bm = 32 * w + 16 * rs + g * 4 + r;
                    const int e = nt * 16 + ln;
                    *(ushort*)((char*)As + bm * 128 + ((2 * e) ^ ((bm & 7) << 4))) =
                        f2bf(acc[rs][nt][r] + bvn[nt]);
                }
        __syncthreads();

        short8 a2[2][2], b2[4][2];
        #pragma unroll
        for (int rs = 0; rs < 2; ++rs) {
            const int row = 32 * w + 16 * rs + ln, sw = (row & 7) << 4;
            #pragma unroll
            for (int kc = 0; kc < 2; ++kc)
                a2[rs][kc] = *(const short8*)((const char*)As + row * 128 + ((kc * 64 + g * 16) ^ sw));
        }
        #pragma unroll
        for (int nt = 0; nt < 4; ++nt) {
            const int rk = nt * 16 + ln, sw = (rk & 7) << 4;
            #pragma unroll
            for (int kc = 0; kc < 2; ++kc)
                b2[nt][kc] = *(const short8*)((const char*)Ws + rk * 128 + ((kc * 64 + g * 16) ^ sw));
        }
        f32x4 yac[2][4];
        #pragma unroll
        for (int rs = 0; rs < 2; ++rs)
            #pragma unroll
            for (int nt = 0; nt < 4; ++nt) {
                yac[rs][nt] = (f32x4){0.f, 0.f, 0.f, 0.f};
                #pragma unroll
                for (int kc = 0; kc < 2; ++kc)
                    yac[rs][nt] = __builtin_amdgcn_mfma_f32_16x16x32_bf16(
                        a2[rs][kc], b2[nt][kc], yac[rs][nt], 0, 0, 0);
            }

        const float* __restrict__ bf2p = (which == 0) ? bfq : bfk;
        float bfv[4];
        #pragma unroll
        for (int nt = 0; nt < 4; ++nt) bfv[nt] = bf2p[nt * 16 + ln];

        ushort* __restrict__ dstF = (which == 0) ? fqd : fkd;
        float csp[4] = {0.f, 0.f, 0.f, 0.f}, csm[4] = {0.f, 0.f, 0.f, 0.f};
        #pragma unroll
        for (int rs = 0; rs < 2; ++rs)
            #pragma unroll
            for (int nt = 0; nt < 4; ++nt)
                #pragma unroll
                for (int r = 0; r < 4; ++r) {
                    const int m = m0 + 32 * w + 16 * rs + g * 4 + r;
                    const int b_ = m >> 11, s_ = m & (kS - 1);
                    const float y = yac[rs][nt][r] + bfv[nt];
                    const ushort hp = f2bf(__expf(y));
                    const ushort hm = f2bf(__expf(-y));
                    const size_t base =
                        ((size_t)(b_ * kH + hh) * kS + s_) * kF + nt * 16 + ln;
                    dstF[base] = hp;
                    dstF[base + 64] = hm;
                    if (which == 1) { csp[nt] += bf2f(hp); csm[nt] += bf2f(hm); }
                }

        if (which == 1) {
            #pragma unroll
            for (int nt = 0; nt < 4; ++nt) {
                csp[nt] += __shfl_xor(csp[nt], 16); csp[nt] += __shfl_xor(csp[nt], 32);
                csm[nt] += __shfl_xor(csm[nt], 16); csm[nt] += __shfl_xor(csm[nt], 32);
            }
            if (g == 0) {
                #pragma unroll
                for (int nt = 0; nt < 4; ++nt) {
                    zsum[w][nt * 16 + ln]      = csp[nt];
                    zsum[w][64 + nt * 16 + ln] = csm[nt];
                }
            }
            __syncthreads();
            if (t < 128) {
                const float s = zsum[0][t] + zsum[1][t] + zsum[2][t] + zsum[3][t];
                const int b_ = m0 >> 11, gr = (m0 & (kS - 1)) >> 7;
                part[((size_t)((b_ * kH + hh) * 16 + gr)) * kF + t] = s;
            }
        }
    }
}

// ---------------- fk column-sum final reduce ----------------
__global__ __launch_bounds__(128) void fksum_red_kernel(
    const float* __restrict__ part, float* __restrict__ fksum)
{
    const int bh = blockIdx.x, e = threadIdx.x;
    float acc = 0.f;
    for (int g = 0; g < 16; ++g) acc += part[((size_t)bh * 16 + g) * kF + e];
    fksum[bh * kF + e] = acc;
}

// ---------------- softmax attention ----------------
__global__ __launch_bounds__(256) void true_attn_kernel(
    const ushort* __restrict__ q, const ushort* __restrict__ k,
    const ushort* __restrict__ vT,
    float* __restrict__ out0, float* __restrict__ out2)
{
    const int orig = blockIdx.y * 32 + blockIdx.x;        // 768 blocks
    const int swz  = (orig & 7) * 96 + (orig >> 3);
    const int bh = swz >> 5, m0 = (swz & 31) * 64;

    const int t = threadIdx.x, lane = t & 63, w = t >> 6;
    const int g = lane >> 4, ln = lane & 15;

    __shared__ __align__(16) ushort Qs[64 * 64];         // 8 KB
    __shared__ __align__(16) ushort KVs[4 * 64 * 64];    // 32 KB: pass1 quad-K; pass2 K=0/1, V=2/3
    __shared__ __align__(16) ushort Ps[64 * 64];         // 8 KB

    const ushort* __restrict__ qb = q  + (size_t)bh * kS * kHD;
    const ushort* __restrict__ kb = k  + (size_t)bh * kS * kHD;
    const ushort* __restrict__ vb = vT + (size_t)bh * kHD * kS;

    stage64x64(Qs, qb + (size_t)m0 * kHD, kHD, t);
    __syncthreads();

    short8 aq[2];
    {
        const int row = 16 * w + ln, sw = (row & 7) << 4;
        #pragma unroll
        for (int kc = 0; kc < 2; ++kc)
            aq[kc] = *(const short8*)((const char*)Qs + row * 128 + ((kc * 64 + g * 16) ^ sw));
    }

    // ---- pass 1: row sums of exp(s); quad-buffered K, prefetch depth 3 ----
    gstage64x64(KVs, kb, kHD, w, lane);
    gstage64x64(KVs + 4096, kb + (size_t)64 * kHD, kHD, w, lane);
    gstage64x64(KVs + 8192, kb + (size_t)128 * kHD, kHD, w, lane);
    float zacc[4] = {0.f, 0.f, 0.f, 0.f};
    for (int tt = 0; tt < 32; ++tt) {
        if (tt + 3 < 32) {
            gstage64x64(KVs + ((tt + 3) & 3) * 4096,
                        kb + (size_t)(tt + 3) * 64 * kHD, kHD, w, lane);
            asm volatile("s_waitcnt vmcnt(6)" ::: "memory");
        } else if (tt == 29) {
            asm volatile("s_waitcnt vmcnt(4)" ::: "memory");
        } else if (tt == 30) {
            asm volatile("s_waitcnt vmcnt(2)" ::: "memory");
        } else {
            asm volatile("s_waitcnt vmcnt(0)" ::: "memory");
        }
        __builtin_amdgcn_sched_barrier(0);
        __builtin_amdgcn_s_barrier();
        const ushort* KsC = KVs + (tt & 3) * 4096;
        #pragma unroll
        for (int nt = 0; nt < 4; ++nt) {
            f32x4 c = {0.f, 0.f, 0.f, 0.f};
            const int rk = nt * 16 + ln, sw = (rk & 7) << 4;
            #pragma unroll
            for (int kc = 0; kc < 2; ++kc) {
                short8 b = *(const short8*)((const char*)KsC + rk * 128 + ((kc * 64 + g * 16) ^ sw));
                c = __builtin_amdgcn_mfma_f32_16x16x32_bf16(aq[kc], b, c, 0, 0, 0);
            }
            #pragma unroll
            for (int r = 0; r < 4; ++r) zacc[r] += __expf(c[r] * 0.125f);
        }
        __builtin_amdgcn_sched_barrier(0);
        __builtin_amdgcn_s_barrier();
    }
    float invl[4];
    #pragma unroll
    for (int r = 0; r < 4; ++r) {
        float z = zacc[r];
        z += __shfl_xor(z, 1); z += __shfl_xor(z, 2);
        z += __shfl_xor(z, 4); z += __shfl_xor(z, 8);
        invl[r] = 1.f / z;
    }

    // ---- pass 2: probs + PV, K/V double-buffered ----
    f32x4 accv[4];
    #pragma unroll
    for (int dt = 0; dt < 4; ++dt) accv[dt] = (f32x4){0.f, 0.f, 0.f, 0.f};

    gstage64x64(KVs, kb, kHD, w, lane);
    gstage64x64(KVs + 2 * 4096, vb, kS, w, lane);
    for (int tt = 0; tt < 32; ++tt) {
        const int cur = tt & 1;
        const int n0 = tt * 64;
        if (tt + 1 < 32) {
            gstage64x64(KVs + (cur ^ 1) * 4096,
                        kb + (size_t)(tt + 1) * 64 * kHD, kHD, w, lane);
            gstage64x64(KVs + (2 + (cur ^ 1)) * 4096,
                        vb + (tt + 1) * 64, kS, w, lane);
            asm volatile("s_waitcnt vmcnt(4)" ::: "memory");
        } else {
            asm volatile("s_waitcnt vmcnt(0)" ::: "memory");
        }
        __builtin_amdgcn_sched_barrier(0);
        __builtin_amdgcn_s_barrier();

        const ushort* KsC = KVs + cur * 4096;
        const ushort* VsC = KVs + (2 + cur) * 4096;
        #pragma unroll
        for (int nt = 0; nt < 4; ++nt) {
            f32x4 c = {0.f, 0.f, 0.f, 0.f};
            const int rk = nt * 16 + ln, sw = (rk & 7) << 4;
            #pragma unroll
            for (int kc = 0; kc < 2; ++kc) {
                short8 b = *(const short8*)((const char*)KsC + rk * 128 + ((kc * 64 + g * 16) ^ sw));
                c = __builtin_amdgcn_mfma_f32_16x16x32_bf16(aq[kc], b, c, 0, 0, 0);
            }
            #pragma unroll
            for (int r = 0; r < 4; ++r) {
                const int prow = 16 * w + g * 4 + r;
                const float p = __expf(c[r] * 0.125f) * invl[r];
                ntst(&out2[((size_t)bh * kS + m0 + prow) * kS + n0 + nt * 16 + ln], p);
                const int pb = prow * 128 + ((2 * (nt * 16 + ln)) ^ ((prow & 7) << 4));
                *(ushort*)((char*)Ps + pb) = f2bf(p);
            }
        }
        asm volatile("s_waitcnt lgkmcnt(0)" ::: "memory");
        __builtin_amdgcn_sched_barrier(0);
        __builtin_amdgcn_s_barrier();

        const int rowp = 16 * w + ln, swp = (rowp & 7) << 4;
        #pragma unroll
        for (int kc = 0; kc < 2; ++kc) {
            short8 pa = *(const short8*)((const char*)Ps + rowp * 128 + ((kc * 64 + g * 16) ^ swp));
            #pragma unroll
            for (int dt = 0; dt < 4; ++dt) {
                const int rv = dt * 16 + ln, swv = (rv & 7) << 4;
                short8 bv = *(const short8*)((const char*)VsC + rv * 128 + ((kc * 64 + g * 16) ^ swv));
                accv[dt] = __builtin_amdgcn_mfma_f32_16x16x32_bf16(pa, bv, accv[dt], 0, 0, 0);
            }
        }
        __builtin_amdgcn_sched_barrier(0);
        __builtin_amdgcn_s_barrier();
    }

    const int b_ = bh / kH, h_ = bh % kH;
    #pragma unroll
    for (int dt = 0; dt < 4; ++dt)
        #pragma unroll
        for (int r = 0; r < 4; ++r) {
            const int prow = 16 * w + g * 4 + r;
            ntst(&out0[((size_t)b_ * kS + m0 + prow) * kD + h_ * kHD + dt * 16 + ln],
                 accv[dt][r]);
        }
}

// ---------------- hedgehog predicted attention ----------------
__global__ __launch_bounds__(256) void pred_attn_kernel(
    const ushort* __restrict__ fq, const ushort* __restrict__ fk,
    const float* __restrict__ fksum, float* __restrict__ out1)
{
    const int orig = blockIdx.y * 32 + blockIdx.x;        // 768 blocks
    const int swz  = (orig & 7) * 96 + (orig >> 3);
    const int bh = swz >> 5, m0 = (swz & 31) * 64;

    const int t = threadIdx.x, lane = t & 63, w = t >> 6;
    const int g = lane >> 4, ln = lane & 15;

    __shared__ __align__(16) ushort Fq[64 * 128];         // 16 KB
    __shared__ __align__(16) ushort Fk[2 * 64 * 128];     // 32 KB dbuf
    __shared__ float fsum[128];
    __shared__ float invz[64];

    const ushort* __restrict__ fqb = fq + (size_t)bh * kS * kF;
    const ushort* __restrict__ fkb = fk + (size_t)bh * kS * kF;

    stage64x128(Fq, fqb + (size_t)m0 * kF, t);
    if (t < 128) fsum[t] = fksum[bh * kF + t];
    __syncthreads();

    short8 a[4];
    {
        const int row = 16 * w + ln, sw = (row & 7) << 4;
        #pragma unroll
        for (int kc = 0; kc < 4; ++kc)
            a[kc] = *(const short8*)((const char*)Fq + row * 256 + ((kc * 64 + g * 16) ^ sw));
    }

    float den = 0.f;
    #pragma unroll
    for (int kc = 0; kc < 4; ++kc)
        #pragma unroll
        for (int j = 0; j < 8; ++j)
            den += bf2f((ushort)a[kc][j]) * fsum[kc * 32 + g * 8 + j];
    den += __shfl_xor(den, 16);
    den += __shfl_xor(den, 32);
    if (g == 0) invz[16 * w + ln] = 1.f / den;
    __syncthreads();
    float invl[4];
    #pragma unroll
    for (int r = 0; r < 4; ++r) invl[r] = invz[16 * w + g * 4 + r];

    gstage64x128(Fk, fkb, w, lane);
    for (int tt = 0; tt < 32; ++tt) {
        const int cur = tt & 1;
        const int n0 = tt * 64;
        if (tt + 1 < 32) {
            gstage64x128(Fk + (cur ^ 1) * 8192, fkb + (size_t)(tt + 1) * 64 * kF, w, lane);
            asm volatile("s_waitcnt vmcnt(4)" ::: "memory");
        } else {
            asm volatile("s_waitcnt vmcnt(0)" ::: "memory");
        }
        __builtin_amdgcn_sched_barrier(0);
        __builtin_amdgcn_s_barrier();

        const ushort* FkC = Fk + cur * 8192;
        #pragma unroll
        for (int nt = 0; nt < 4; ++nt) {
            f32x4 c = {0.f, 0.f, 0.f, 0.f};
            const int rk = nt * 16 + ln, sw = (rk & 7) << 4;
            #pragma unroll
            for (int kc = 0; kc < 4; ++kc) {
                short8 b = *(const short8*)((const char*)FkC + rk * 256 + ((kc * 64 + g * 16) ^ sw));
                c = __builtin_amdgcn_mfma_f32_16x16x32_bf16(a[kc], b, c, 0, 0, 0);
            }
            #pragma unroll
            for (int r = 0; r < 4; ++r)
                ntst(&out1[((size_t)bh * kS + m0 + 16 * w + g * 4 + r) * kS + n0 + nt * 16 + ln],
                     c[r] * invl[r]);
        }
        __builtin_amdgcn_sched_barrier(0);
        __builtin_amdgcn_s_barrier();
    }
}

}  // namespace

extern "C" void kernel_launch(void* const* d_in, const int* in_sizes, int n_in,
                              void* d_out, int out_size, void* d_ws, size_t ws_size,
                              hipStream_t stream)
{
    (void)in_sizes; (void)n_in; (void)out_size; (void)ws_size;

    const float* hidden = (const float*)d_in[0];
    const float* Wq = (const float*)d_in[1];
    const float* bq = (const float*)d_in[2];
    const float* Wk = (const float*)d_in[3];
    const float* bk = (const float*)d_in[4];
    const float* Wv = (const float*)d_in[5];
    const float* bv = (const float*)d_in[6];
    const float* Wfq = (const float*)d_in[7];
    const float* bfq = (const float*)d_in[8];
    const float* Wfk = (const float*)d_in[9];
    const float* bfk = (const float*)d_in[10];

    float* out = (float*)d_out;
    float* out0 = out;                                   // outputs   [B,S,D]
    float* out1 = out0 + (size_t)kB * kS * kD;           // pred_attns[B,H,S,S]
    float* out2 = out1 + (size_t)kBH * kS * kS;          // true_attns[B,H,S,S]

    float* part = (float*)d_ws;                          // [kBH*16*kF]
    float* fks  = part + (size_t)kBH * 16 * kF;          // [kBH*kF]
    ushort* hb  = (ushort*)(fks + (size_t)kBH * kF);     // hidden bf16
    ushort* Wqb = hb  + (size_t)kB * kS * kD;
    ushort* Wkb = Wqb + (size_t)kD * kD;
    ushort* Wvb = Wkb + (size_t)kD * kD;
    ushort* qw  = Wvb + (size_t)kD * kD;
    ushort* kw  = qw  + (size_t)kBH * kS * kHD;
    ushort* vTw = kw  + (size_t)kBH * kS * kHD;
    ushort* fqw = vTw + (size_t)kBH * kS * kHD;
    ushort* fkw = fqw + (size_t)kBH * kS * kF;

    cast_kernel<<<dim3(512, 4), 256, 0, stream>>>(
        hidden, Wq, Wk, Wv, hb, Wqb, Wkb, Wvb);
    qkv_mfma_kernel<<<dim3(kB * kS / 128, kD / 64, 3), 256, 0, stream>>>(
        hb, Wqb, Wkb, Wvb, bq, bk, bv,
        Wfq, bfq, Wfk, bfk,
        qw, kw, vTw, fqw, fkw, part);
    fksum_red_kernel<<<dim3(kBH), 128, 0, stream>>>(part, fks);
    true_attn_kernel<<<dim3(kS / 64, kBH), 256, 0, stream>>>(qw, kw, vTw, out0, out2);
    pred_attn_kernel<<<dim3(kS / 64, kBH), 256, 0, stream>>>(fqw, fkw, fks, out1);
}

// Round 11
// 326.942 us; speedup vs baseline: 1.0208x; 1.0208x over previous
//
#include <hip/hip_runtime.h>
#include <math.h>

namespace {

constexpr int kB = 2, kS = 2048, kD = 768, kH = 12, kHD = 64, kF = 128, kBH = kB * kH;

typedef __attribute__((ext_vector_type(8))) short short8;
typedef __attribute__((ext_vector_type(4))) short short4v;
typedef __attribute__((ext_vector_type(4))) float f32x4;

__device__ __forceinline__ ushort f2bf(float x) {
    union { float f; unsigned u; } v; v.f = x;
    return (ushort)((v.u + 0x7fffu + ((v.u >> 16) & 1u)) >> 16);
}
__device__ __forceinline__ float bf2f(ushort u) {
    union { unsigned u; float f; } v; v.u = ((unsigned)u) << 16; return v.f;
}

__device__ __forceinline__ void gload16(const ushort* g, void* lds) {
    __builtin_amdgcn_global_load_lds(
        (const __attribute__((address_space(1))) void*)g,
        (__attribute__((address_space(3))) void*)lds, 16, 0, 0);
}

// Async-stage 64x64 bf16 tile; LDS rows 128B; swizzle via pre-permuted global src.
__device__ __forceinline__ void gstage64x64(ushort* ldsBase, const ushort* g,
                                            size_t strideElems, int w, int lane) {
    #pragma unroll
    for (int j = 0; j < 2; ++j) {
        const int row = 16 * w + 8 * j + (lane >> 3);
        const int chunk = lane & 7;
        const ushort* gp = g + (size_t)row * strideElems + ((chunk ^ (row & 7)) * 8);
        void* lp = (char*)ldsBase + (16 * w + 8 * j) * 128;
        gload16(gp, lp);
    }
}

// Async-stage 64x128 bf16 tile (rows 256B).
__device__ __forceinline__ void gstage64x128(ushort* ldsBase, const ushort* g,
                                             int w, int lane) {
    #pragma unroll
    for (int j = 0; j < 4; ++j) {
        const int row = 16 * w + 4 * j + (lane >> 4);
        const int chunk = lane & 15;
        const ushort* gp = g + (size_t)row * kF + ((chunk ^ (row & 7)) * 8);
        void* lp = (char*)ldsBase + (16 * w + 4 * j) * 256;
        gload16(gp, lp);
    }
}

// Reg-path stage (outside main loops).
__device__ __forceinline__ void stage64x64(ushort* dst, const ushort* srcRow0,
                                           size_t rowStride, int t) {
    const int row = t >> 2, ce = (t & 3) * 16;
    const ushort* s = srcRow0 + (size_t)row * rowStride + ce;
    uint4 u0 = *(const uint4*)s;
    uint4 u1 = *(const uint4*)(s + 8);
    const int sw = (row & 7) << 4;
    *(uint4*)((char*)dst + row * 128 + ((ce * 2) ^ sw)) = u0;
    *(uint4*)((char*)dst + row * 128 + ((ce * 2 + 16) ^ sw)) = u1;
}

__device__ __forceinline__ void stage64x128(ushort* dst, const ushort* srcRow0, int t) {
    const int row = t >> 2, ce = (t & 3) * 32;
    const ushort* s = srcRow0 + (size_t)row * kF + ce;
    const int sw = (row & 7) << 4;
    #pragma unroll
    for (int u = 0; u < 4; ++u) {
        uint4 x = *(const uint4*)(s + u * 8);
        *(uint4*)((char*)dst + row * 256 + ((ce * 2 + u * 16) ^ sw)) = x;
    }
}

// ---------------- fp32 -> bf16 casts ----------------
__global__ __launch_bounds__(256) void cast_kernel(
    const float* __restrict__ s0, const float* __restrict__ s1,
    const float* __restrict__ s2, const float* __restrict__ s3,
    ushort* __restrict__ d0, ushort* __restrict__ d1,
    ushort* __restrict__ d2, ushort* __restrict__ d3)
{
    const int seg = blockIdx.y;
    const float* src = seg == 0 ? s0 : seg == 1 ? s1 : seg == 2 ? s2 : s3;
    ushort* dst      = seg == 0 ? d0 : seg == 1 ? d1 : seg == 2 ? d2 : d3;
    const int n4 = (seg == 0 ? kB * kS * kD : kD * kD) / 4;
    for (int i = blockIdx.x * 256 + threadIdx.x; i < n4; i += gridDim.x * 256) {
        float4 v = *(const float4*)&src[(size_t)i * 4];
        short4v o;
        o[0] = (short)f2bf(v.x); o[1] = (short)f2bf(v.y);
        o[2] = (short)f2bf(v.z); o[3] = (short)f2bf(v.w);
        *(short4v*)&dst[(size_t)i * 4] = o;
    }
}

// ---------------- QKV projection + fused hedgehog feature map ----------------
__global__ __launch_bounds__(256) void qkv_mfma_kernel(
    const ushort* __restrict__ hb,
    const ushort* __restrict__ Wqb, const ushort* __restrict__ Wkb,
    const ushort* __restrict__ Wvb,
    const float* __restrict__ bq, const float* __restrict__ bk,
    const float* __restrict__ bv,
    const float* __restrict__ Wfq, const float* __restrict__ bfq,
    const float* __restrict__ Wfk, const float* __restrict__ bfk,
    ushort* __restrict__ qd, ushort* __restrict__ kd, ushort* __restrict__ vTd,
    ushort* __restrict__ fqd, ushort* __restrict__ fkd,
    float* __restrict__ part)
{
    const int which = blockIdx.z;
    const ushort* __restrict__ Wb  = which == 0 ? Wqb : which == 1 ? Wkb : Wvb;
    const float* __restrict__ bias = which == 0 ? bq : which == 1 ? bk : bv;

    const int m0 = blockIdx.x * 128;
    const int n0 = blockIdx.y * 64;
    const int t = threadIdx.x, lane = t & 63, w = t >> 6;
    const int g = lane >> 4, ln = lane & 15;

    __shared__ __align__(16) ushort As[128 * 64];
    __shared__ __align__(16) ushort Bs[64 * 64];
    __shared__ __align__(16) ushort Ws[64 * 64];
    __shared__ float zsum[4][128];

    if (which < 2) {
        const float* __restrict__ Wf = (which == 0) ? Wfq : Wfk;
        const int row = t >> 2, ce = (t & 3) * 16;
        ushort tmp[16];
        #pragma unroll
        for (int c = 0; c < 16; c += 4) {
            float4 u = *(const float4*)&Wf[(size_t)row * 64 + ce + c];
            tmp[c + 0] = f2bf(u.x); tmp[c + 1] = f2bf(u.y);
            tmp[c + 2] = f2bf(u.z); tmp[c + 3] = f2bf(u.w);
        }
        const int sw = (row & 7) << 4;
        *(uint4*)((char*)Ws + row * 128 + ((ce * 2) ^ sw)) = *(uint4*)&tmp[0];
        *(uint4*)((char*)Ws + row * 128 + ((ce * 2 + 16) ^ sw)) = *(uint4*)&tmp[8];
    }

    f32x4 acc[2][4];
    #pragma unroll
    for (int rs = 0; rs < 2; ++rs)
        #pragma unroll
        for (int nt = 0; nt < 4; ++nt) acc[rs][nt] = (f32x4){0.f, 0.f, 0.f, 0.f};

    for (int k0 = 0; k0 < kD; k0 += 64) {
        __syncthreads();
        #pragma unroll
        for (int u = 0; u < 4; ++u) {
            const int ci = u * 256 + t, row = ci >> 3, c = ci & 7;
            uint4 x = *(const uint4*)&hb[(size_t)(m0 + row) * kD + k0 + c * 8];
            *(uint4*)((char*)As + row * 128 + ((c * 16) ^ ((row & 7) << 4))) = x;
        }
        #pragma unroll
        for (int u = 0; u < 2; ++u) {
            const int ci = u * 256 + t, row = ci >> 3, c = ci & 7;
            uint4 x = *(const uint4*)&Wb[(size_t)(n0 + row) * kD + k0 + c * 8];
            *(uint4*)((char*)Bs + row * 128 + ((c * 16) ^ ((row & 7) << 4))) = x;
        }
        __syncthreads();

        short8 a[2][2], b[4][2];
        #pragma unroll
        for (int rs = 0; rs < 2; ++rs) {
            const int row = 32 * w + 16 * rs + ln, sw = (row & 7) << 4;
            #pragma unroll
            for (int kc = 0; kc < 2; ++kc)
                a[rs][kc] = *(const short8*)((const char*)As + row * 128 + ((kc * 64 + g * 16) ^ sw));
        }
        #pragma unroll
        for (int nt = 0; nt < 4; ++nt) {
            const int rk = nt * 16 + ln, sw = (rk & 7) << 4;
            #pragma unroll
            for (int kc = 0; kc < 2; ++kc)
                b[nt][kc] = *(const short8*)((const char*)Bs + rk * 128 + ((kc * 64 + g * 16) ^ sw));
        }
        #pragma unroll
        for (int rs = 0; rs < 2; ++rs)
            #pragma unroll
            for (int nt = 0; nt < 4; ++nt)
                #pragma unroll
                for (int kc = 0; kc < 2; ++kc)
                    acc[rs][nt] = __builtin_amdgcn_mfma_f32_16x16x32_bf16(
                        a[rs][kc], b[nt][kc], acc[rs][nt], 0, 0, 0);
    }

    const int hh = n0 >> 6;
    float bvn[4];
    #pragma unroll
    for (int nt = 0; nt < 4; ++nt) bvn[nt] = bias[n0 + nt * 16 + ln];

    if (which < 2) {
        ushort* __restrict__ dst = (which == 0) ? qd : kd;
        #pragma unroll
        for (int rs = 0; rs < 2; ++rs)
            #pragma unroll
            for (int nt = 0; nt < 4; ++nt)
                #pragma unroll
                for (int r = 0; r < 4; ++r) {
                    const int m = m0 + 32 * w + 16 * rs + g * 4 + r;
                    const int b_ = m >> 11, s_ = m & (kS - 1);
                    dst[((size_t)(b_ * kH + hh) * kS + s_) * kHD + nt * 16 + ln] =
                        f2bf(acc[rs][nt][r] + bvn[nt]);
                }
    } else {
        #pragma unroll
        for (int rs = 0; rs < 2; ++rs)
            #pragma unroll
            for (int nt = 0; nt < 4; ++nt) {
                const int m = m0 + 32 * w + 16 * rs + g * 4;
                const int b_ = m >> 11, s_ = m & (kS - 1);
                const int d = nt * 16 + ln;
                short4v o;
                #pragma unroll
                for (int r = 0; r < 4; ++r) o[r] = (short)f2bf(acc[rs][nt][r] + bvn[nt]);
                *(short4v*)&vTd[((size_t)(b_ * kH + hh) * kHD + d) * kS + s_] = o;
            }
    }

    // ---- fused feature map: f = exp(+/-(x @ Wf^T + bf)) ----
    if (which < 2) {
        __syncthreads();
        #pragma unroll
        for (int rs = 0; rs < 2; ++rs)
            #pragma unroll
            for (int nt = 0; nt < 4; ++nt)
                #pragma unroll
                for (int r = 0; r < 4; ++r) {
                    const int bm = 32 * w + 16 * rs + g * 4 + r;
                    const int e = nt * 16 + ln;
                    *(ushort*)((char*)As + bm * 128 + ((2 * e) ^ ((bm & 7) << 4))) =
                        f2bf(acc[rs][nt][r] + bvn[nt]);
                }
        __syncthreads();

        short8 a2[2][2], b2[4][2];
        #pragma unroll
        for (int rs = 0; rs < 2; ++rs) {
            const int row = 32 * w + 16 * rs + ln, sw = (row & 7) << 4;
            #pragma unroll
            for (int kc = 0; kc < 2; ++kc)
                a2[rs][kc] = *(const short8*)((const char*)As + row * 128 + ((kc * 64 + g * 16) ^ sw));
        }
        #pragma unroll
        for (int nt = 0; nt < 4; ++nt) {
            const int rk = nt * 16 + ln, sw = (rk & 7) << 4;
            #pragma unroll
            for (int kc = 0; kc < 2; ++kc)
                b2[nt][kc] = *(const short8*)((const char*)Ws + rk * 128 + ((kc * 64 + g * 16) ^ sw));
        }
        f32x4 yac[2][4];
        #pragma unroll
        for (int rs = 0; rs < 2; ++rs)
            #pragma unroll
            for (int nt = 0; nt < 4; ++nt) {
                yac[rs][nt] = (f32x4){0.f, 0.f, 0.f, 0.f};
                #pragma unroll
                for (int kc = 0; kc < 2; ++kc)
                    yac[rs][nt] = __builtin_amdgcn_mfma_f32_16x16x32_bf16(
                        a2[rs][kc], b2[nt][kc], yac[rs][nt], 0, 0, 0);
            }

        const float* __restrict__ bf2p = (which == 0) ? bfq : bfk;
        float bfv[4];
        #pragma unroll
        for (int nt = 0; nt < 4; ++nt) bfv[nt] = bf2p[nt * 16 + ln];

        ushort* __restrict__ dstF = (which == 0) ? fqd : fkd;
        float csp[4] = {0.f, 0.f, 0.f, 0.f}, csm[4] = {0.f, 0.f, 0.f, 0.f};
        #pragma unroll
        for (int rs = 0; rs < 2; ++rs)
            #pragma unroll
            for (int nt = 0; nt < 4; ++nt)
                #pragma unroll
                for (int r = 0; r < 4; ++r) {
                    const int m = m0 + 32 * w + 16 * rs + g * 4 + r;
                    const int b_ = m >> 11, s_ = m & (kS - 1);
                    const float y = yac[rs][nt][r] + bfv[nt];
                    const ushort hp = f2bf(__expf(y));
                    const ushort hm = f2bf(__expf(-y));
                    const size_t base =
                        ((size_t)(b_ * kH + hh) * kS + s_) * kF + nt * 16 + ln;
                    dstF[base] = hp;
                    dstF[base + 64] = hm;
                    if (which == 1) { csp[nt] += bf2f(hp); csm[nt] += bf2f(hm); }
                }

        if (which == 1) {
            #pragma unroll
            for (int nt = 0; nt < 4; ++nt) {
                csp[nt] += __shfl_xor(csp[nt], 16); csp[nt] += __shfl_xor(csp[nt], 32);
                csm[nt] += __shfl_xor(csm[nt], 16); csm[nt] += __shfl_xor(csm[nt], 32);
            }
            if (g == 0) {
                #pragma unroll
                for (int nt = 0; nt < 4; ++nt) {
                    zsum[w][nt * 16 + ln]      = csp[nt];
                    zsum[w][64 + nt * 16 + ln] = csm[nt];
                }
            }
            __syncthreads();
            if (t < 128) {
                const float s = zsum[0][t] + zsum[1][t] + zsum[2][t] + zsum[3][t];
                const int b_ = m0 >> 11, gr = (m0 & (kS - 1)) >> 7;
                part[((size_t)((b_ * kH + hh) * 16 + gr)) * kF + t] = s;
            }
        }
    }
}

// ---------------- fk column-sum final reduce ----------------
__global__ __launch_bounds__(128) void fksum_red_kernel(
    const float* __restrict__ part, float* __restrict__ fksum)
{
    const int bh = blockIdx.x, e = threadIdx.x;
    float acc = 0.f;
    for (int g = 0; g < 16; ++g) acc += part[((size_t)bh * 16 + g) * kF + e];
    fksum[bh * kF + e] = acc;
}

// ---------------- fused attention: true (VALU-heavy) + pred (MFMA/store-heavy) ----------------
// 1536 blocks; xcd = orig&7, which = (orig>>3)&1, idx = (orig>>4)*8 + (orig&7).
// Each XCD gets alternating true/pred block groups with preserved panel locality.
__global__ __launch_bounds__(256) void attn_fused_kernel(
    const ushort* __restrict__ q, const ushort* __restrict__ k,
    const ushort* __restrict__ vT,
    const ushort* __restrict__ fq, const ushort* __restrict__ fk,
    const float* __restrict__ fksum,
    float* __restrict__ out0, float* __restrict__ out1, float* __restrict__ out2)
{
    const int orig = blockIdx.x;
    const int which = (orig >> 3) & 1;
    const int idx = (orig >> 4) * 8 + (orig & 7);          // [0,768)
    const int swz = (idx & 7) * 96 + (idx >> 3);
    const int bh = swz >> 5, m0 = (swz & 31) * 64;

    const int t = threadIdx.x, lane = t & 63, w = t >> 6;
    const int g = lane >> 4, ln = lane & 15;

    __shared__ __align__(16) ushort sbuf[24576];           // 48 KB, union of both layouts
    __shared__ float smallf[192];                          // fsum[128] + invz[64]

    if (which == 0) {
        // ================= true attention =================
        ushort* Qs  = sbuf;                 // 64x64
        ushort* Ks0 = sbuf + 4096;
        ushort* Ks1 = sbuf + 8192;
        ushort* Vs0 = sbuf + 12288;
        ushort* Vs1 = sbuf + 16384;
        ushort* Ps  = sbuf + 20480;

        const ushort* __restrict__ qb = q  + (size_t)bh * kS * kHD;
        const ushort* __restrict__ kb = k  + (size_t)bh * kS * kHD;
        const ushort* __restrict__ vb = vT + (size_t)bh * kHD * kS;

        stage64x64(Qs, qb + (size_t)m0 * kHD, kHD, t);
        __syncthreads();

        short8 aq[2];
        {
            const int row = 16 * w + ln, sw = (row & 7) << 4;
            #pragma unroll
            for (int kc = 0; kc < 2; ++kc)
                aq[kc] = *(const short8*)((const char*)Qs + row * 128 + ((kc * 64 + g * 16) ^ sw));
        }

        // ---- pass 1: row sums of exp(s), K double-buffered ----
        gstage64x64(Ks0, kb, kHD, w, lane);
        float zacc[4] = {0.f, 0.f, 0.f, 0.f};
        for (int tt = 0; tt < 32; ++tt) {
            ushort* KsC = (tt & 1) ? Ks1 : Ks0;
            ushort* KsN = (tt & 1) ? Ks0 : Ks1;
            if (tt + 1 < 32) {
                gstage64x64(KsN, kb + (size_t)(tt + 1) * 64 * kHD, kHD, w, lane);
                asm volatile("s_waitcnt vmcnt(2)" ::: "memory");
            } else {
                asm volatile("s_waitcnt vmcnt(0)" ::: "memory");
            }
            __builtin_amdgcn_sched_barrier(0);
            __builtin_amdgcn_s_barrier();
            #pragma unroll
            for (int nt = 0; nt < 4; ++nt) {
                f32x4 c = {0.f, 0.f, 0.f, 0.f};
                const int rk = nt * 16 + ln, sw = (rk & 7) << 4;
                #pragma unroll
                for (int kc = 0; kc < 2; ++kc) {
                    short8 b = *(const short8*)((const char*)KsC + rk * 128 + ((kc * 64 + g * 16) ^ sw));
                    c = __builtin_amdgcn_mfma_f32_16x16x32_bf16(aq[kc], b, c, 0, 0, 0);
                }
                #pragma unroll
                for (int r = 0; r < 4; ++r) zacc[r] += __expf(c[r] * 0.125f);
            }
            __builtin_amdgcn_sched_barrier(0);
            __builtin_amdgcn_s_barrier();
        }
        float invl[4];
        #pragma unroll
        for (int r = 0; r < 4; ++r) {
            float z = zacc[r];
            z += __shfl_xor(z, 1); z += __shfl_xor(z, 2);
            z += __shfl_xor(z, 4); z += __shfl_xor(z, 8);
            invl[r] = 1.f / z;
        }

        // ---- pass 2: probs + PV, K/V double-buffered ----
        f32x4 accv[4];
        #pragma unroll
        for (int dt = 0; dt < 4; ++dt) accv[dt] = (f32x4){0.f, 0.f, 0.f, 0.f};

        gstage64x64(Ks0, kb, kHD, w, lane);
        gstage64x64(Vs0, vb, kS, w, lane);
        for (int tt = 0; tt < 32; ++tt) {
            const int n0 = tt * 64;
            ushort* KsC = (tt & 1) ? Ks1 : Ks0;
            ushort* VsC = (tt & 1) ? Vs1 : Vs0;
            ushort* KsN = (tt & 1) ? Ks0 : Ks1;
            ushort* VsN = (tt & 1) ? Vs0 : Vs1;
            if (tt + 1 < 32) {
                gstage64x64(KsN, kb + (size_t)(tt + 1) * 64 * kHD, kHD, w, lane);
                gstage64x64(VsN, vb + (tt + 1) * 64, kS, w, lane);
                asm volatile("s_waitcnt vmcnt(4)" ::: "memory");
            } else {
                asm volatile("s_waitcnt vmcnt(0)" ::: "memory");
            }
            __builtin_amdgcn_sched_barrier(0);
            __builtin_amdgcn_s_barrier();

            #pragma unroll
            for (int nt = 0; nt < 4; ++nt) {
                f32x4 c = {0.f, 0.f, 0.f, 0.f};
                const int rk = nt * 16 + ln, sw = (rk & 7) << 4;
                #pragma unroll
                for (int kc = 0; kc < 2; ++kc) {
                    short8 b = *(const short8*)((const char*)KsC + rk * 128 + ((kc * 64 + g * 16) ^ sw));
                    c = __builtin_amdgcn_mfma_f32_16x16x32_bf16(aq[kc], b, c, 0, 0, 0);
                }
                #pragma unroll
                for (int r = 0; r < 4; ++r) {
                    const int prow = 16 * w + g * 4 + r;
                    const float p = __expf(c[r] * 0.125f) * invl[r];
                    out2[((size_t)bh * kS + m0 + prow) * kS + n0 + nt * 16 + ln] = p;
                    const int pb = prow * 128 + ((2 * (nt * 16 + ln)) ^ ((prow & 7) << 4));
                    *(ushort*)((char*)Ps + pb) = f2bf(p);
                }
            }
            asm volatile("s_waitcnt lgkmcnt(0)" ::: "memory");
            __builtin_amdgcn_sched_barrier(0);
            __builtin_amdgcn_s_barrier();

            const int rowp = 16 * w + ln, swp = (rowp & 7) << 4;
            #pragma unroll
            for (int kc = 0; kc < 2; ++kc) {
                short8 pa = *(const short8*)((const char*)Ps + rowp * 128 + ((kc * 64 + g * 16) ^ swp));
                #pragma unroll
                for (int dt = 0; dt < 4; ++dt) {
                    const int rv = dt * 16 + ln, swv = (rv & 7) << 4;
                    short8 bv = *(const short8*)((const char*)VsC + rv * 128 + ((kc * 64 + g * 16) ^ swv));
                    accv[dt] = __builtin_amdgcn_mfma_f32_16x16x32_bf16(pa, bv, accv[dt], 0, 0, 0);
                }
            }
            __builtin_amdgcn_sched_barrier(0);
            __builtin_amdgcn_s_barrier();
        }

        const int b_ = bh / kH, h_ = bh % kH;
        #pragma unroll
        for (int dt = 0; dt < 4; ++dt)
            #pragma unroll
            for (int r = 0; r < 4; ++r) {
                const int prow = 16 * w + g * 4 + r;
                out0[((size_t)b_ * kS + m0 + prow) * kD + h_ * kHD + dt * 16 + ln] = accv[dt][r];
            }
    } else {
        // ================= hedgehog predicted attention =================
        ushort* Fq  = sbuf;                 // 64x128
        ushort* Fk0 = sbuf + 8192;
        ushort* Fk1 = sbuf + 16384;
        float* fsum = smallf;
        float* invz = smallf + 128;

        const ushort* __restrict__ fqb = fq + (size_t)bh * kS * kF;
        const ushort* __restrict__ fkb = fk + (size_t)bh * kS * kF;

        stage64x128(Fq, fqb + (size_t)m0 * kF, t);
        if (t < 128) fsum[t] = fksum[bh * kF + t];
        __syncthreads();

        short8 a[4];
        {
            const int row = 16 * w + ln, sw = (row & 7) << 4;
            #pragma unroll
            for (int kc = 0; kc < 4; ++kc)
                a[kc] = *(const short8*)((const char*)Fq + row * 256 + ((kc * 64 + g * 16) ^ sw));
        }

        float den = 0.f;
        #pragma unroll
        for (int kc = 0; kc < 4; ++kc)
            #pragma unroll
            for (int j = 0; j < 8; ++j)
                den += bf2f((ushort)a[kc][j]) * fsum[kc * 32 + g * 8 + j];
        den += __shfl_xor(den, 16);
        den += __shfl_xor(den, 32);
        if (g == 0) invz[16 * w + ln] = 1.f / den;
        __syncthreads();
        float invl[4];
        #pragma unroll
        for (int r = 0; r < 4; ++r) invl[r] = invz[16 * w + g * 4 + r];

        gstage64x128(Fk0, fkb, w, lane);
        for (int tt = 0; tt < 32; ++tt) {
            const int n0 = tt * 64;
            ushort* FkC = (tt & 1) ? Fk1 : Fk0;
            ushort* FkN = (tt & 1) ? Fk0 : Fk1;
            if (tt + 1 < 32) {
                gstage64x128(FkN, fkb + (size_t)(tt + 1) * 64 * kF, w, lane);
                asm volatile("s_waitcnt vmcnt(4)" ::: "memory");
            } else {
                asm volatile("s_waitcnt vmcnt(0)" ::: "memory");
            }
            __builtin_amdgcn_sched_barrier(0);
            __builtin_amdgcn_s_barrier();

            #pragma unroll
            for (int nt = 0; nt < 4; ++nt) {
                f32x4 c = {0.f, 0.f, 0.f, 0.f};
                const int rk = nt * 16 + ln, sw = (rk & 7) << 4;
                #pragma unroll
                for (int kc = 0; kc < 4; ++kc) {
                    short8 b = *(const short8*)((const char*)FkC + rk * 256 + ((kc * 64 + g * 16) ^ sw));
                    c = __builtin_amdgcn_mfma_f32_16x16x32_bf16(a[kc], b, c, 0, 0, 0);
                }
                #pragma unroll
                for (int r = 0; r < 4; ++r)
                    out1[((size_t)bh * kS + m0 + 16 * w + g * 4 + r) * kS + n0 + nt * 16 + ln] =
                        c[r] * invl[r];
            }
            __builtin_amdgcn_sched_barrier(0);
            __builtin_amdgcn_s_barrier();
        }
    }
}

}  // namespace

extern "C" void kernel_launch(void* const* d_in, const int* in_sizes, int n_in,
                              void* d_out, int out_size, void* d_ws, size_t ws_size,
                              hipStream_t stream)
{
    (void)in_sizes; (void)n_in; (void)out_size; (void)ws_size;

    const float* hidden = (const float*)d_in[0];
    const float* Wq = (const float*)d_in[1];
    const float* bq = (const float*)d_in[2];
    const float* Wk = (const float*)d_in[3];
    const float* bk = (const float*)d_in[4];
    const float* Wv = (const float*)d_in[5];
    const float* bv = (const float*)d_in[6];
    const float* Wfq = (const float*)d_in[7];
    const float* bfq = (const float*)d_in[8];
    const float* Wfk = (const float*)d_in[9];
    const float* bfk = (const float*)d_in[10];

    float* out = (float*)d_out;
    float* out0 = out;                                   // outputs   [B,S,D]
    float* out1 = out0 + (size_t)kB * kS * kD;           // pred_attns[B,H,S,S]
    float* out2 = out1 + (size_t)kBH * kS * kS;          // true_attns[B,H,S,S]

    float* part = (float*)d_ws;                          // [kBH*16*kF]
    float* fks  = part + (size_t)kBH * 16 * kF;          // [kBH*kF]
    ushort* hb  = (ushort*)(fks + (size_t)kBH * kF);     // hidden bf16
    ushort* Wqb = hb  + (size_t)kB * kS * kD;
    ushort* Wkb = Wqb + (size_t)kD * kD;
    ushort* Wvb = Wkb + (size_t)kD * kD;
    ushort* qw  = Wvb + (size_t)kD * kD;
    ushort* kw  = qw  + (size_t)kBH * kS * kHD;
    ushort* vTw = kw  + (size_t)kBH * kS * kHD;
    ushort* fqw = vTw + (size_t)kBH * kS * kHD;
    ushort* fkw = fqw + (size_t)kBH * kS * kF;

    cast_kernel<<<dim3(512, 4), 256, 0, stream>>>(
        hidden, Wq, Wk, Wv, hb, Wqb, Wkb, Wvb);
    qkv_mfma_kernel<<<dim3(kB * kS / 128, kD / 64, 3), 256, 0, stream>>>(
        hb, Wqb, Wkb, Wvb, bq, bk, bv,
        Wfq, bfq, Wfk, bfk,
        qw, kw, vTw, fqw, fkw, part);
    fksum_red_kernel<<<dim3(kBH), 128, 0, stream>>>(part, fks);
    attn_fused_kernel<<<dim3(2 * kS / 64 * kBH / 16 * 16), 256, 0, stream>>>(
        qw, kw, vTw, fqw, fkw, fks, out0, out1, out2);
}

// Round 12
// 315.927 us; speedup vs baseline: 1.0564x; 1.0349x over previous
//
#include <hip/hip_runtime.h>
#include <math.h>

namespace {

constexpr int kB = 2, kS = 2048, kD = 768, kH = 12, kHD = 64, kF = 128, kBH = kB * kH;

typedef __attribute__((ext_vector_type(8))) short short8;
typedef __attribute__((ext_vector_type(4))) short short4v;
typedef __attribute__((ext_vector_type(4))) float f32x4;

__device__ __forceinline__ ushort f2bf(float x) {
    union { float f; unsigned u; } v; v.f = x;
    return (ushort)((v.u + 0x7fffu + ((v.u >> 16) & 1u)) >> 16);
}
__device__ __forceinline__ float bf2f(ushort u) {
    union { unsigned u; float f; } v; v.u = ((unsigned)u) << 16; return v.f;
}

__device__ __forceinline__ void gload16(const ushort* g, void* lds) {
    __builtin_amdgcn_global_load_lds(
        (const __attribute__((address_space(1))) void*)g,
        (__attribute__((address_space(3))) void*)lds, 16, 0, 0);
}

// Async-stage 64x64 bf16 tile; LDS rows 128B; swizzle via pre-permuted global src.
__device__ __forceinline__ void gstage64x64(ushort* ldsBase, const ushort* g,
                                            size_t strideElems, int w, int lane) {
    #pragma unroll
    for (int j = 0; j < 2; ++j) {
        const int row = 16 * w + 8 * j + (lane >> 3);
        const int chunk = lane & 7;
        const ushort* gp = g + (size_t)row * strideElems + ((chunk ^ (row & 7)) * 8);
        void* lp = (char*)ldsBase + (16 * w + 8 * j) * 128;
        gload16(gp, lp);
    }
}

// Async-stage 64x128 bf16 tile (rows 256B).
__device__ __forceinline__ void gstage64x128(ushort* ldsBase, const ushort* g,
                                             int w, int lane) {
    #pragma unroll
    for (int j = 0; j < 4; ++j) {
        const int row = 16 * w + 4 * j + (lane >> 4);
        const int chunk = lane & 15;
        const ushort* gp = g + (size_t)row * kF + ((chunk ^ (row & 7)) * 8);
        void* lp = (char*)ldsBase + (16 * w + 4 * j) * 256;
        gload16(gp, lp);
    }
}

// Reg-path stage (outside main loops).
__device__ __forceinline__ void stage64x64(ushort* dst, const ushort* srcRow0,
                                           size_t rowStride, int t) {
    const int row = t >> 2, ce = (t & 3) * 16;
    const ushort* s = srcRow0 + (size_t)row * rowStride + ce;
    uint4 u0 = *(const uint4*)s;
    uint4 u1 = *(const uint4*)(s + 8);
    const int sw = (row & 7) << 4;
    *(uint4*)((char*)dst + row * 128 + ((ce * 2) ^ sw)) = u0;
    *(uint4*)((char*)dst + row * 128 + ((ce * 2 + 16) ^ sw)) = u1;
}

__device__ __forceinline__ void stage64x128(ushort* dst, const ushort* srcRow0, int t) {
    const int row = t >> 2, ce = (t & 3) * 32;
    const ushort* s = srcRow0 + (size_t)row * kF + ce;
    const int sw = (row & 7) << 4;
    #pragma unroll
    for (int u = 0; u < 4; ++u) {
        uint4 x = *(const uint4*)(s + u * 8);
        *(uint4*)((char*)dst + row * 256 + ((ce * 2 + u * 16) ^ sw)) = x;
    }
}

// ---------------- fp32 -> bf16 casts ----------------
__global__ __launch_bounds__(256) void cast_kernel(
    const float* __restrict__ s0, const float* __restrict__ s1,
    const float* __restrict__ s2, const float* __restrict__ s3,
    ushort* __restrict__ d0, ushort* __restrict__ d1,
    ushort* __restrict__ d2, ushort* __restrict__ d3)
{
    const int seg = blockIdx.y;
    const float* src = seg == 0 ? s0 : seg == 1 ? s1 : seg == 2 ? s2 : s3;
    ushort* dst      = seg == 0 ? d0 : seg == 1 ? d1 : seg == 2 ? d2 : d3;
    const int n4 = (seg == 0 ? kB * kS * kD : kD * kD) / 4;
    for (int i = blockIdx.x * 256 + threadIdx.x; i < n4; i += gridDim.x * 256) {
        float4 v = *(const float4*)&src[(size_t)i * 4];
        short4v o;
        o[0] = (short)f2bf(v.x); o[1] = (short)f2bf(v.y);
        o[2] = (short)f2bf(v.z); o[3] = (short)f2bf(v.w);
        *(short4v*)&dst[(size_t)i * 4] = o;
    }
}

// ---------------- QKV projection + fused hedgehog feature map ----------------
__global__ __launch_bounds__(256) void qkv_mfma_kernel(
    const ushort* __restrict__ hb,
    const ushort* __restrict__ Wqb, const ushort* __restrict__ Wkb,
    const ushort* __restrict__ Wvb,
    const float* __restrict__ bq, const float* __restrict__ bk,
    const float* __restrict__ bv,
    const float* __restrict__ Wfq, const float* __restrict__ bfq,
    const float* __restrict__ Wfk, const float* __restrict__ bfk,
    ushort* __restrict__ qd, ushort* __restrict__ kd, ushort* __restrict__ vTd,
    ushort* __restrict__ fqd, ushort* __restrict__ fkd,
    float* __restrict__ part)
{
    const int which = blockIdx.z;
    const ushort* __restrict__ Wb  = which == 0 ? Wqb : which == 1 ? Wkb : Wvb;
    const float* __restrict__ bias = which == 0 ? bq : which == 1 ? bk : bv;

    const int m0 = blockIdx.x * 128;
    const int n0 = blockIdx.y * 64;
    const int t = threadIdx.x, lane = t & 63, w = t >> 6;
    const int g = lane >> 4, ln = lane & 15;

    __shared__ __align__(16) ushort As[128 * 64];
    __shared__ __align__(16) ushort Bs[64 * 64];
    __shared__ __align__(16) ushort Ws[64 * 64];
    __shared__ float zsum[4][128];

    if (which < 2) {
        const float* __restrict__ Wf = (which == 0) ? Wfq : Wfk;
        const int row = t >> 2, ce = (t & 3) * 16;
        ushort tmp[16];
        #pragma unroll
        for (int c = 0; c < 16; c += 4) {
            float4 u = *(const float4*)&Wf[(size_t)row * 64 + ce + c];
            tmp[c + 0] = f2bf(u.x); tmp[c + 1] = f2bf(u.y);
            tmp[c + 2] = f2bf(u.z); tmp[c + 3] = f2bf(u.w);
        }
        const int sw = (row & 7) << 4;
        *(uint4*)((char*)Ws + row * 128 + ((ce * 2) ^ sw)) = *(uint4*)&tmp[0];
        *(uint4*)((char*)Ws + row * 128 + ((ce * 2 + 16) ^ sw)) = *(uint4*)&tmp[8];
    }

    f32x4 acc[2][4];
    #pragma unroll
    for (int rs = 0; rs < 2; ++rs)
        #pragma unroll
        for (int nt = 0; nt < 4; ++nt) acc[rs][nt] = (f32x4){0.f, 0.f, 0.f, 0.f};

    for (int k0 = 0; k0 < kD; k0 += 64) {
        __syncthreads();
        #pragma unroll
        for (int u = 0; u < 4; ++u) {
            const int ci = u * 256 + t, row = ci >> 3, c = ci & 7;
            uint4 x = *(const uint4*)&hb[(size_t)(m0 + row) * kD + k0 + c * 8];
            *(uint4*)((char*)As + row * 128 + ((c * 16) ^ ((row & 7) << 4))) = x;
        }
        #pragma unroll
        for (int u = 0; u < 2; ++u) {
            const int ci = u * 256 + t, row = ci >> 3, c = ci & 7;
            uint4 x = *(const uint4*)&Wb[(size_t)(n0 + row) * kD + k0 + c * 8];
            *(uint4*)((char*)Bs + row * 128 + ((c * 16) ^ ((row & 7) << 4))) = x;
        }
        __syncthreads();

        short8 a[2][2], b[4][2];
        #pragma unroll
        for (int rs = 0; rs < 2; ++rs) {
            const int row = 32 * w + 16 * rs + ln, sw = (row & 7) << 4;
            #pragma unroll
            for (int kc = 0; kc < 2; ++kc)
                a[rs][kc] = *(const short8*)((const char*)As + row * 128 + ((kc * 64 + g * 16) ^ sw));
        }
        #pragma unroll
        for (int nt = 0; nt < 4; ++nt) {
            const int rk = nt * 16 + ln, sw = (rk & 7) << 4;
            #pragma unroll
            for (int kc = 0; kc < 2; ++kc)
                b[nt][kc] = *(const short8*)((const char*)Bs + rk * 128 + ((kc * 64 + g * 16) ^ sw));
        }
        #pragma unroll
        for (int rs = 0; rs < 2; ++rs)
            #pragma unroll
            for (int nt = 0; nt < 4; ++nt)
                #pragma unroll
                for (int kc = 0; kc < 2; ++kc)
                    acc[rs][nt] = __builtin_amdgcn_mfma_f32_16x16x32_bf16(
                        a[rs][kc], b[nt][kc], acc[rs][nt], 0, 0, 0);
    }

    const int hh = n0 >> 6;
    float bvn[4];
    #pragma unroll
    for (int nt = 0; nt < 4; ++nt) bvn[nt] = bias[n0 + nt * 16 + ln];

    if (which < 2) {
        ushort* __restrict__ dst = (which == 0) ? qd : kd;
        #pragma unroll
        for (int rs = 0; rs < 2; ++rs)
            #pragma unroll
            for (int nt = 0; nt < 4; ++nt)
                #pragma unroll
                for (int r = 0; r < 4; ++r) {
                    const int m = m0 + 32 * w + 16 * rs + g * 4 + r;
                    const int b_ = m >> 11, s_ = m & (kS - 1);
                    dst[((size_t)(b_ * kH + hh) * kS + s_) * kHD + nt * 16 + ln] =
                        f2bf(acc[rs][nt][r] + bvn[nt]);
                }
    } else {
        #pragma unroll
        for (int rs = 0; rs < 2; ++rs)
            #pragma unroll
            for (int nt = 0; nt < 4; ++nt) {
                const int m = m0 + 32 * w + 16 * rs + g * 4;
                const int b_ = m >> 11, s_ = m & (kS - 1);
                const int d = nt * 16 + ln;
                short4v o;
                #pragma unroll
                for (int r = 0; r < 4; ++r) o[r] = (short)f2bf(acc[rs][nt][r] + bvn[nt]);
                *(short4v*)&vTd[((size_t)(b_ * kH + hh) * kHD + d) * kS + s_] = o;
            }
    }

    // ---- fused feature map: f = exp(+/-(x @ Wf^T + bf)) ----
    if (which < 2) {
        __syncthreads();
        #pragma unroll
        for (int rs = 0; rs < 2; ++rs)
            #pragma unroll
            for (int nt = 0; nt < 4; ++nt)
                #pragma unroll
                for (int r = 0; r < 4; ++r) {
                    const int bm = 32 * w + 16 * rs + g * 4 + r;
                    const int e = nt * 16 + ln;
                    *(ushort*)((char*)As + bm * 128 + ((2 * e) ^ ((bm & 7) << 4))) =
                        f2bf(acc[rs][nt][r] + bvn[nt]);
                }
        __syncthreads();

        short8 a2[2][2], b2[4][2];
        #pragma unroll
        for (int rs = 0; rs < 2; ++rs) {
            const int row = 32 * w + 16 * rs + ln, sw = (row & 7) << 4;
            #pragma unroll
            for (int kc = 0; kc < 2; ++kc)
                a2[rs][kc] = *(const short8*)((const char*)As + row * 128 + ((kc * 64 + g * 16) ^ sw));
        }
        #pragma unroll
        for (int nt = 0; nt < 4; ++nt) {
            const int rk = nt * 16 + ln, sw = (rk & 7) << 4;
            #pragma unroll
            for (int kc = 0; kc < 2; ++kc)
                b2[nt][kc] = *(const short8*)((const char*)Ws + rk * 128 + ((kc * 64 + g * 16) ^ sw));
        }
        f32x4 yac[2][4];
        #pragma unroll
        for (int rs = 0; rs < 2; ++rs)
            #pragma unroll
            for (int nt = 0; nt < 4; ++nt) {
                yac[rs][nt] = (f32x4){0.f, 0.f, 0.f, 0.f};
                #pragma unroll
                for (int kc = 0; kc < 2; ++kc)
                    yac[rs][nt] = __builtin_amdgcn_mfma_f32_16x16x32_bf16(
                        a2[rs][kc], b2[nt][kc], yac[rs][nt], 0, 0, 0);
            }

        const float* __restrict__ bf2p = (which == 0) ? bfq : bfk;
        float bfv[4];
        #pragma unroll
        for (int nt = 0; nt < 4; ++nt) bfv[nt] = bf2p[nt * 16 + ln];

        ushort* __restrict__ dstF = (which == 0) ? fqd : fkd;
        float csp[4] = {0.f, 0.f, 0.f, 0.f}, csm[4] = {0.f, 0.f, 0.f, 0.f};
        #pragma unroll
        for (int rs = 0; rs < 2; ++rs)
            #pragma unroll
            for (int nt = 0; nt < 4; ++nt)
                #pragma unroll
                for (int r = 0; r < 4; ++r) {
                    const int m = m0 + 32 * w + 16 * rs + g * 4 + r;
                    const int b_ = m >> 11, s_ = m & (kS - 1);
                    const float y = yac[rs][nt][r] + bfv[nt];
                    const ushort hp = f2bf(__expf(y));
                    const ushort hm = f2bf(__expf(-y));
                    const size_t base =
                        ((size_t)(b_ * kH + hh) * kS + s_) * kF + nt * 16 + ln;
                    dstF[base] = hp;
                    dstF[base + 64] = hm;
                    if (which == 1) { csp[nt] += bf2f(hp); csm[nt] += bf2f(hm); }
                }

        if (which == 1) {
            #pragma unroll
            for (int nt = 0; nt < 4; ++nt) {
                csp[nt] += __shfl_xor(csp[nt], 16); csp[nt] += __shfl_xor(csp[nt], 32);
                csm[nt] += __shfl_xor(csm[nt], 16); csm[nt] += __shfl_xor(csm[nt], 32);
            }
            if (g == 0) {
                #pragma unroll
                for (int nt = 0; nt < 4; ++nt) {
                    zsum[w][nt * 16 + ln]      = csp[nt];
                    zsum[w][64 + nt * 16 + ln] = csm[nt];
                }
            }
            __syncthreads();
            if (t < 128) {
                const float s = zsum[0][t] + zsum[1][t] + zsum[2][t] + zsum[3][t];
                const int b_ = m0 >> 11, gr = (m0 & (kS - 1)) >> 7;
                part[((size_t)((b_ * kH + hh) * 16 + gr)) * kF + t] = s;
            }
        }
    }
}

// ---------------- fk column-sum final reduce ----------------
__global__ __launch_bounds__(128) void fksum_red_kernel(
    const float* __restrict__ part, float* __restrict__ fksum)
{
    const int bh = blockIdx.x, e = threadIdx.x;
    float acc = 0.f;
    for (int g = 0; g < 16; ++g) acc += part[((size_t)bh * 16 + g) * kF + e];
    fksum[bh * kF + e] = acc;
}

// ---------------- softmax attention: reduced-barrier pipeline ----------------
__global__ __launch_bounds__(256) void true_attn_kernel(
    const ushort* __restrict__ q, const ushort* __restrict__ k,
    const ushort* __restrict__ vT,
    float* __restrict__ out0, float* __restrict__ out2)
{
    const int orig = blockIdx.y * 32 + blockIdx.x;        // 768 blocks
    const int swz  = (orig & 7) * 96 + (orig >> 3);
    const int bh = swz >> 5, m0 = (swz & 31) * 64;

    const int t = threadIdx.x, lane = t & 63, w = t >> 6;
    const int g = lane >> 4, ln = lane & 15;

    __shared__ __align__(16) ushort Qs[64 * 64];         // 8 KB
    __shared__ __align__(16) ushort KVs[4 * 64 * 64];    // 32 KB: pass1 quad-K; pass2 K=0/1, V=2/3
    __shared__ __align__(16) ushort Ps[64 * 64];         // 8 KB

    const ushort* __restrict__ qb = q  + (size_t)bh * kS * kHD;
    const ushort* __restrict__ kb = k  + (size_t)bh * kS * kHD;
    const ushort* __restrict__ vb = vT + (size_t)bh * kHD * kS;

    stage64x64(Qs, qb + (size_t)m0 * kHD, kHD, t);
    __syncthreads();

    short8 aq[2];
    {
        const int row = 16 * w + ln, sw = (row & 7) << 4;
        #pragma unroll
        for (int kc = 0; kc < 2; ++kc)
            aq[kc] = *(const short8*)((const char*)Qs + row * 128 + ((kc * 64 + g * 16) ^ sw));
    }

    // ---- pass 1: quad-buffered K, prefetch depth 2, ONE barrier per iter ----
    // gstage at iter u targets buf[(u+2)&3], last read at iter u-2; all waves
    // past barrier(u) have completed compute(u-1) -> target free. No end barrier.
    gstage64x64(KVs, kb, kHD, w, lane);
    gstage64x64(KVs + 4096, kb + (size_t)64 * kHD, kHD, w, lane);
    float zacc[4] = {0.f, 0.f, 0.f, 0.f};
    for (int tt = 0; tt < 32; ++tt) {
        if (tt + 2 < 32) {
            gstage64x64(KVs + ((tt + 2) & 3) * 4096,
                        kb + (size_t)(tt + 2) * 64 * kHD, kHD, w, lane);
            asm volatile("s_waitcnt vmcnt(4)" ::: "memory");
        } else if (tt == 30) {
            asm volatile("s_waitcnt vmcnt(2)" ::: "memory");
        } else {
            asm volatile("s_waitcnt vmcnt(0)" ::: "memory");
        }
        __builtin_amdgcn_sched_barrier(0);
        __builtin_amdgcn_s_barrier();
        const ushort* KsC = KVs + (tt & 3) * 4096;
        #pragma unroll
        for (int nt = 0; nt < 4; ++nt) {
            f32x4 c = {0.f, 0.f, 0.f, 0.f};
            const int rk = nt * 16 + ln, sw = (rk & 7) << 4;
            #pragma unroll
            for (int kc = 0; kc < 2; ++kc) {
                short8 b = *(const short8*)((const char*)KsC + rk * 128 + ((kc * 64 + g * 16) ^ sw));
                c = __builtin_amdgcn_mfma_f32_16x16x32_bf16(aq[kc], b, c, 0, 0, 0);
            }
            #pragma unroll
            for (int r = 0; r < 4; ++r) zacc[r] += __expf(c[r] * 0.125f);
        }
    }
    float invl[4];
    #pragma unroll
    for (int r = 0; r < 4; ++r) {
        float z = zacc[r];
        z += __shfl_xor(z, 1); z += __shfl_xor(z, 2);
        z += __shfl_xor(z, 4); z += __shfl_xor(z, 8);
        invl[r] = 1.f / z;
    }
    __syncthreads();   // pass-1 stragglers must finish before pass-2 overwrites KVs

    // ---- pass 2: probs + PV, K/V double-buffered; Ps is wave-private
    //      (writes rows [16w,16w+16), PV reads same rows) -> no barrier after
    //      the probs phase, only own-wave lgkmcnt. ----
    f32x4 accv[4];
    #pragma unroll
    for (int dt = 0; dt < 4; ++dt) accv[dt] = (f32x4){0.f, 0.f, 0.f, 0.f};

    gstage64x64(KVs, kb, kHD, w, lane);
    gstage64x64(KVs + 2 * 4096, vb, kS, w, lane);
    for (int tt = 0; tt < 32; ++tt) {
        const int cur = tt & 1;
        const int n0 = tt * 64;
        if (tt + 1 < 32) {
            gstage64x64(KVs + (cur ^ 1) * 4096,
                        kb + (size_t)(tt + 1) * 64 * kHD, kHD, w, lane);
            gstage64x64(KVs + (2 + (cur ^ 1)) * 4096,
                        vb + (tt + 1) * 64, kS, w, lane);
            asm volatile("s_waitcnt vmcnt(4)" ::: "memory");
        } else {
            asm volatile("s_waitcnt vmcnt(0)" ::: "memory");
        }
        __builtin_amdgcn_sched_barrier(0);
        __builtin_amdgcn_s_barrier();

        const ushort* KsC = KVs + cur * 4096;
        const ushort* VsC = KVs + (2 + cur) * 4096;
        #pragma unroll
        for (int nt = 0; nt < 4; ++nt) {
            f32x4 c = {0.f, 0.f, 0.f, 0.f};
            const int rk = nt * 16 + ln, sw = (rk & 7) << 4;
            #pragma unroll
            for (int kc = 0; kc < 2; ++kc) {
                short8 b = *(const short8*)((const char*)KsC + rk * 128 + ((kc * 64 + g * 16) ^ sw));
                c = __builtin_amdgcn_mfma_f32_16x16x32_bf16(aq[kc], b, c, 0, 0, 0);
            }
            #pragma unroll
            for (int r = 0; r < 4; ++r) {
                const int prow = 16 * w + g * 4 + r;
                const float p = __expf(c[r] * 0.125f) * invl[r];
                out2[((size_t)bh * kS + m0 + prow) * kS + n0 + nt * 16 + ln] = p;
                const int pb = prow * 128 + ((2 * (nt * 16 + ln)) ^ ((prow & 7) << 4));
                *(ushort*)((char*)Ps + pb) = f2bf(p);
            }
        }
        asm volatile("s_waitcnt lgkmcnt(0)" ::: "memory");
        __builtin_amdgcn_sched_barrier(0);
        // no s_barrier: Ps rows are wave-private

        const int rowp = 16 * w + ln, swp = (rowp & 7) << 4;
        #pragma unroll
        for (int kc = 0; kc < 2; ++kc) {
            short8 pa = *(const short8*)((const char*)Ps + rowp * 128 + ((kc * 64 + g * 16) ^ swp));
            #pragma unroll
            for (int dt = 0; dt < 4; ++dt) {
                const int rv = dt * 16 + ln, swv = (rv & 7) << 4;
                short8 bv = *(const short8*)((const char*)VsC + rv * 128 + ((kc * 64 + g * 16) ^ swv));
                accv[dt] = __builtin_amdgcn_mfma_f32_16x16x32_bf16(pa, bv, accv[dt], 0, 0, 0);
            }
        }
        __builtin_amdgcn_sched_barrier(0);
        __builtin_amdgcn_s_barrier();   // protect K/V buffers before next-iter gstage
    }

    const int b_ = bh / kH, h_ = bh % kH;
    #pragma unroll
    for (int dt = 0; dt < 4; ++dt)
        #pragma unroll
        for (int r = 0; r < 4; ++r) {
            const int prow = 16 * w + g * 4 + r;
            out0[((size_t)b_ * kS + m0 + prow) * kD + h_ * kHD + dt * 16 + ln] = accv[dt][r];
        }
}

// ---------------- hedgehog predicted attention (R8-identical) ----------------
__global__ __launch_bounds__(256) void pred_attn_kernel(
    const ushort* __restrict__ fq, const ushort* __restrict__ fk,
    const float* __restrict__ fksum, float* __restrict__ out1)
{
    const int orig = blockIdx.y * 32 + blockIdx.x;        // 768 blocks
    const int swz  = (orig & 7) * 96 + (orig >> 3);
    const int bh = swz >> 5, m0 = (swz & 31) * 64;

    const int t = threadIdx.x, lane = t & 63, w = t >> 6;
    const int g = lane >> 4, ln = lane & 15;

    __shared__ __align__(16) ushort Fq[64 * 128];         // 16 KB
    __shared__ __align__(16) ushort Fk[2 * 64 * 128];     // 32 KB dbuf
    __shared__ float fsum[128];
    __shared__ float invz[64];

    const ushort* __restrict__ fqb = fq + (size_t)bh * kS * kF;
    const ushort* __restrict__ fkb = fk + (size_t)bh * kS * kF;

    stage64x128(Fq, fqb + (size_t)m0 * kF, t);
    if (t < 128) fsum[t] = fksum[bh * kF + t];
    __syncthreads();

    short8 a[4];
    {
        const int row = 16 * w + ln, sw = (row & 7) << 4;
        #pragma unroll
        for (int kc = 0; kc < 4; ++kc)
            a[kc] = *(const short8*)((const char*)Fq + row * 256 + ((kc * 64 + g * 16) ^ sw));
    }

    float den = 0.f;
    #pragma unroll
    for (int kc = 0; kc < 4; ++kc)
        #pragma unroll
        for (int j = 0; j < 8; ++j)
            den += bf2f((ushort)a[kc][j]) * fsum[kc * 32 + g * 8 + j];
    den += __shfl_xor(den, 16);
    den += __shfl_xor(den, 32);
    if (g == 0) invz[16 * w + ln] = 1.f / den;
    __syncthreads();
    float invl[4];
    #pragma unroll
    for (int r = 0; r < 4; ++r) invl[r] = invz[16 * w + g * 4 + r];

    gstage64x128(Fk, fkb, w, lane);
    for (int tt = 0; tt < 32; ++tt) {
        const int cur = tt & 1;
        const int n0 = tt * 64;
        if (tt + 1 < 32) {
            gstage64x128(Fk + (cur ^ 1) * 8192, fkb + (size_t)(tt + 1) * 64 * kF, w, lane);
            asm volatile("s_waitcnt vmcnt(4)" ::: "memory");
        } else {
            asm volatile("s_waitcnt vmcnt(0)" ::: "memory");
        }
        __builtin_amdgcn_sched_barrier(0);
        __builtin_amdgcn_s_barrier();

        const ushort* FkC = Fk + cur * 8192;
        #pragma unroll
        for (int nt = 0; nt < 4; ++nt) {
            f32x4 c = {0.f, 0.f, 0.f, 0.f};
            const int rk = nt * 16 + ln, sw = (rk & 7) << 4;
            #pragma unroll
            for (int kc = 0; kc < 4; ++kc) {
                short8 b = *(const short8*)((const char*)FkC + rk * 256 + ((kc * 64 + g * 16) ^ sw));
                c = __builtin_amdgcn_mfma_f32_16x16x32_bf16(a[kc], b, c, 0, 0, 0);
            }
            #pragma unroll
            for (int r = 0; r < 4; ++r)
                out1[((size_t)bh * kS + m0 + 16 * w + g * 4 + r) * kS + n0 + nt * 16 + ln] =
                    c[r] * invl[r];
        }
        __builtin_amdgcn_sched_barrier(0);
        __builtin_amdgcn_s_barrier();
    }
}

}  // namespace

extern "C" void kernel_launch(void* const* d_in, const int* in_sizes, int n_in,
                              void* d_out, int out_size, void* d_ws, size_t ws_size,
                              hipStream_t stream)
{
    (void)in_sizes; (void)n_in; (void)out_size; (void)ws_size;

    const float* hidden = (const float*)d_in[0];
    const float* Wq = (const float*)d_in[1];
    const float* bq = (const float*)d_in[2];
    const float* Wk = (const float*)d_in[3];
    const float* bk = (const float*)d_in[4];
    const float* Wv = (const float*)d_in[5];
    const float* bv = (const float*)d_in[6];
    const float* Wfq = (const float*)d_in[7];
    const float* bfq = (const float*)d_in[8];
    const float* Wfk = (const float*)d_in[9];
    const float* bfk = (const float*)d_in[10];

    float* out = (float*)d_out;
    float* out0 = out;                                   // outputs   [B,S,D]
    float* out1 = out0 + (size_t)kB * kS * kD;           // pred_attns[B,H,S,S]
    float* out2 = out1 + (size_t)kBH * kS * kS;          // true_attns[B,H,S,S]

    float* part = (float*)d_ws;                          // [kBH*16*kF]
    float* fks  = part + (size_t)kBH * 16 * kF;          // [kBH*kF]
    ushort* hb  = (ushort*)(fks + (size_t)kBH * kF);     // hidden bf16
    ushort* Wqb = hb  + (size_t)kB * kS * kD;
    ushort* Wkb = Wqb + (size_t)kD * kD;
    ushort* Wvb = Wkb + (size_t)kD * kD;
    ushort* qw  = Wvb + (size_t)kD * kD;
    ushort* kw  = qw  + (size_t)kBH * kS * kHD;
    ushort* vTw = kw  + (size_t)kBH * kS * kHD;
    ushort* fqw = vTw + (size_t)kBH * kS * kHD;
    ushort* fkw = fqw + (size_t)kBH * kS * kF;

    cast_kernel<<<dim3(512, 4), 256, 0, stream>>>(
        hidden, Wq, Wk, Wv, hb, Wqb, Wkb, Wvb);
    qkv_mfma_kernel<<<dim3(kB * kS / 128, kD / 64, 3), 256, 0, stream>>>(
        hb, Wqb, Wkb, Wvb, bq, bk, bv,
        Wfq, bfq, Wfk, bfk,
        qw, kw, vTw, fqw, fkw, part);
    fksum_red_kernel<<<dim3(kBH), 128, 0, stream>>>(part, fks);
    true_attn_kernel<<<dim3(kS / 64, kBH), 256, 0, stream>>>(qw, kw, vTw, out0, out2);
    pred_attn_kernel<<<dim3(kS / 64, kBH), 256, 0, stream>>>(fqw, fkw, fks, out1);
}

// Round 13
// 314.573 us; speedup vs baseline: 1.0610x; 1.0043x over previous
//
#include <hip/hip_runtime.h>
#include <math.h>

namespace {

constexpr int kB = 2, kS = 2048, kD = 768, kH = 12, kHD = 64, kF = 128, kBH = kB * kH;

typedef __attribute__((ext_vector_type(8))) short short8;
typedef __attribute__((ext_vector_type(4))) short short4v;
typedef __attribute__((ext_vector_type(4))) float f32x4;

__device__ __forceinline__ ushort f2bf(float x) {
    union { float f; unsigned u; } v; v.f = x;
    return (ushort)((v.u + 0x7fffu + ((v.u >> 16) & 1u)) >> 16);
}
__device__ __forceinline__ float bf2f(ushort u) {
    union { unsigned u; float f; } v; v.u = ((unsigned)u) << 16; return v.f;
}

__device__ __forceinline__ void gload16(const ushort* g, void* lds) {
    __builtin_amdgcn_global_load_lds(
        (const __attribute__((address_space(1))) void*)g,
        (__attribute__((address_space(3))) void*)lds, 16, 0, 0);
}

// Async-stage 64x64 bf16 tile; LDS rows 128B; swizzle via pre-permuted global src.
__device__ __forceinline__ void gstage64x64(ushort* ldsBase, const ushort* g,
                                            size_t strideElems, int w, int lane) {
    #pragma unroll
    for (int j = 0; j < 2; ++j) {
        const int row = 16 * w + 8 * j + (lane >> 3);
        const int chunk = lane & 7;
        const ushort* gp = g + (size_t)row * strideElems + ((chunk ^ (row & 7)) * 8);
        void* lp = (char*)ldsBase + (16 * w + 8 * j) * 128;
        gload16(gp, lp);
    }
}

// Async-stage 128x64 bf16 tile (rows 128B); wave w covers rows [32w, 32w+32).
__device__ __forceinline__ void gstageA128(ushort* ldsBase, const ushort* g,
                                           size_t strideElems, int w, int lane) {
    #pragma unroll
    for (int j = 0; j < 4; ++j) {
        const int row = 32 * w + 8 * j + (lane >> 3);
        const int chunk = lane & 7;
        const ushort* gp = g + (size_t)row * strideElems + ((chunk ^ (row & 7)) * 8);
        void* lp = (char*)ldsBase + (32 * w + 8 * j) * 128;
        gload16(gp, lp);
    }
}

// Async-stage 64x128 bf16 tile (rows 256B).
__device__ __forceinline__ void gstage64x128(ushort* ldsBase, const ushort* g,
                                             int w, int lane) {
    #pragma unroll
    for (int j = 0; j < 4; ++j) {
        const int row = 16 * w + 4 * j + (lane >> 4);
        const int chunk = lane & 15;
        const ushort* gp = g + (size_t)row * kF + ((chunk ^ (row & 7)) * 8);
        void* lp = (char*)ldsBase + (16 * w + 4 * j) * 256;
        gload16(gp, lp);
    }
}

// Reg-path stage (outside main loops).
__device__ __forceinline__ void stage64x64(ushort* dst, const ushort* srcRow0,
                                           size_t rowStride, int t) {
    const int row = t >> 2, ce = (t & 3) * 16;
    const ushort* s = srcRow0 + (size_t)row * rowStride + ce;
    uint4 u0 = *(const uint4*)s;
    uint4 u1 = *(const uint4*)(s + 8);
    const int sw = (row & 7) << 4;
    *(uint4*)((char*)dst + row * 128 + ((ce * 2) ^ sw)) = u0;
    *(uint4*)((char*)dst + row * 128 + ((ce * 2 + 16) ^ sw)) = u1;
}

__device__ __forceinline__ void stage64x128(ushort* dst, const ushort* srcRow0, int t) {
    const int row = t >> 2, ce = (t & 3) * 32;
    const ushort* s = srcRow0 + (size_t)row * kF + ce;
    const int sw = (row & 7) << 4;
    #pragma unroll
    for (int u = 0; u < 4; ++u) {
        uint4 x = *(const uint4*)(s + u * 8);
        *(uint4*)((char*)dst + row * 256 + ((ce * 2 + u * 16) ^ sw)) = x;
    }
}

// ---------------- fp32 -> bf16 casts ----------------
__global__ __launch_bounds__(256) void cast_kernel(
    const float* __restrict__ s0, const float* __restrict__ s1,
    const float* __restrict__ s2, const float* __restrict__ s3,
    ushort* __restrict__ d0, ushort* __restrict__ d1,
    ushort* __restrict__ d2, ushort* __restrict__ d3)
{
    const int seg = blockIdx.y;
    const float* src = seg == 0 ? s0 : seg == 1 ? s1 : seg == 2 ? s2 : s3;
    ushort* dst      = seg == 0 ? d0 : seg == 1 ? d1 : seg == 2 ? d2 : d3;
    const int n4 = (seg == 0 ? kB * kS * kD : kD * kD) / 4;
    for (int i = blockIdx.x * 256 + threadIdx.x; i < n4; i += gridDim.x * 256) {
        float4 v = *(const float4*)&src[(size_t)i * 4];
        short4v o;
        o[0] = (short)f2bf(v.x); o[1] = (short)f2bf(v.y);
        o[2] = (short)f2bf(v.z); o[3] = (short)f2bf(v.w);
        *(short4v*)&dst[(size_t)i * 4] = o;
    }
}

// ---------------- QKV projection + fused hedgehog feature map ----------------
// Staging now via global_load_lds (width 16), same 2-barrier loop.
__global__ __launch_bounds__(256) void qkv_mfma_kernel(
    const ushort* __restrict__ hb,
    const ushort* __restrict__ Wqb, const ushort* __restrict__ Wkb,
    const ushort* __restrict__ Wvb,
    const float* __restrict__ bq, const float* __restrict__ bk,
    const float* __restrict__ bv,
    const float* __restrict__ Wfq, const float* __restrict__ bfq,
    const float* __restrict__ Wfk, const float* __restrict__ bfk,
    ushort* __restrict__ qd, ushort* __restrict__ kd, ushort* __restrict__ vTd,
    ushort* __restrict__ fqd, ushort* __restrict__ fkd,
    float* __restrict__ part)
{
    const int which = blockIdx.z;
    const ushort* __restrict__ Wb  = which == 0 ? Wqb : which == 1 ? Wkb : Wvb;
    const float* __restrict__ bias = which == 0 ? bq : which == 1 ? bk : bv;

    const int m0 = blockIdx.x * 128;
    const int n0 = blockIdx.y * 64;
    const int t = threadIdx.x, lane = t & 63, w = t >> 6;
    const int g = lane >> 4, ln = lane & 15;

    __shared__ __align__(16) ushort As[128 * 64];
    __shared__ __align__(16) ushort Bs[64 * 64];
    __shared__ __align__(16) ushort Ws[64 * 64];
    __shared__ float zsum[4][128];

    if (which < 2) {
        const float* __restrict__ Wf = (which == 0) ? Wfq : Wfk;
        const int row = t >> 2, ce = (t & 3) * 16;
        ushort tmp[16];
        #pragma unroll
        for (int c = 0; c < 16; c += 4) {
            float4 u = *(const float4*)&Wf[(size_t)row * 64 + ce + c];
            tmp[c + 0] = f2bf(u.x); tmp[c + 1] = f2bf(u.y);
            tmp[c + 2] = f2bf(u.z); tmp[c + 3] = f2bf(u.w);
        }
        const int sw = (row & 7) << 4;
        *(uint4*)((char*)Ws + row * 128 + ((ce * 2) ^ sw)) = *(uint4*)&tmp[0];
        *(uint4*)((char*)Ws + row * 128 + ((ce * 2 + 16) ^ sw)) = *(uint4*)&tmp[8];
    }

    f32x4 acc[2][4];
    #pragma unroll
    for (int rs = 0; rs < 2; ++rs)
        #pragma unroll
        for (int nt = 0; nt < 4; ++nt) acc[rs][nt] = (f32x4){0.f, 0.f, 0.f, 0.f};

    for (int k0 = 0; k0 < kD; k0 += 64) {
        gstageA128(As, hb + (size_t)m0 * kD + k0, kD, w, lane);
        gstage64x64(Bs, Wb + (size_t)n0 * kD + k0, kD, w, lane);
        asm volatile("s_waitcnt vmcnt(0)" ::: "memory");
        __builtin_amdgcn_sched_barrier(0);
        __builtin_amdgcn_s_barrier();

        short8 a[2][2], b[4][2];
        #pragma unroll
        for (int rs = 0; rs < 2; ++rs) {
            const int row = 32 * w + 16 * rs + ln, sw = (row & 7) << 4;
            #pragma unroll
            for (int kc = 0; kc < 2; ++kc)
                a[rs][kc] = *(const short8*)((const char*)As + row * 128 + ((kc * 64 + g * 16) ^ sw));
        }
        #pragma unroll
        for (int nt = 0; nt < 4; ++nt) {
            const int rk = nt * 16 + ln, sw = (rk & 7) << 4;
            #pragma unroll
            for (int kc = 0; kc < 2; ++kc)
                b[nt][kc] = *(const short8*)((const char*)Bs + rk * 128 + ((kc * 64 + g * 16) ^ sw));
        }
        #pragma unroll
        for (int rs = 0; rs < 2; ++rs)
            #pragma unroll
            for (int nt = 0; nt < 4; ++nt)
                #pragma unroll
                for (int kc = 0; kc < 2; ++kc)
                    acc[rs][nt] = __builtin_amdgcn_mfma_f32_16x16x32_bf16(
                        a[rs][kc], b[nt][kc], acc[rs][nt], 0, 0, 0);
        asm volatile("s_waitcnt lgkmcnt(0)" ::: "memory");
        __builtin_amdgcn_sched_barrier(0);
        __builtin_amdgcn_s_barrier();
    }

    const int hh = n0 >> 6;
    float bvn[4];
    #pragma unroll
    for (int nt = 0; nt < 4; ++nt) bvn[nt] = bias[n0 + nt * 16 + ln];

    if (which < 2) {
        ushort* __restrict__ dst = (which == 0) ? qd : kd;
        #pragma unroll
        for (int rs = 0; rs < 2; ++rs)
            #pragma unroll
            for (int nt = 0; nt < 4; ++nt)
                #pragma unroll
                for (int r = 0; r < 4; ++r) {
                    const int m = m0 + 32 * w + 16 * rs + g * 4 + r;
                    const int b_ = m >> 11, s_ = m & (kS - 1);
                    dst[((size_t)(b_ * kH + hh) * kS + s_) * kHD + nt * 16 + ln] =
                        f2bf(acc[rs][nt][r] + bvn[nt]);
                }
    } else {
        #pragma unroll
        for (int rs = 0; rs < 2; ++rs)
            #pragma unroll
            for (int nt = 0; nt < 4; ++nt) {
                const int m = m0 + 32 * w + 16 * rs + g * 4;
                const int b_ = m >> 11, s_ = m & (kS - 1);
                const int d = nt * 16 + ln;
                short4v o;
                #pragma unroll
                for (int r = 0; r < 4; ++r) o[r] = (short)f2bf(acc[rs][nt][r] + bvn[nt]);
                *(short4v*)&vTd[((size_t)(b_ * kH + hh) * kHD + d) * kS + s_] = o;
            }
    }

    // ---- fused feature map: f = exp(+/-(x @ Wf^T + bf)) ----
    if (which < 2) {
        __syncthreads();
        #pragma unroll
        for (int rs = 0; rs < 2; ++rs)
            #pragma unroll
            for (int nt = 0; nt < 4; ++nt)
                #pragma unroll
                for (int r = 0; r < 4; ++r) {
                    const int bm = 32 * w + 16 * rs + g * 4 + r;
                    const int e = nt * 16 + ln;
                    *(ushort*)((char*)As + bm * 128 + ((2 * e) ^ ((bm & 7) << 4))) =
                        f2bf(acc[rs][nt][r] + bvn[nt]);
                }
        __syncthreads();

        short8 a2[2][2], b2[4][2];
        #pragma unroll
        for (int rs = 0; rs < 2; ++rs) {
            const int row = 32 * w + 16 * rs + ln, sw = (row & 7) << 4;
            #pragma unroll
            for (int kc = 0; kc < 2; ++kc)
                a2[rs][kc] = *(const short8*)((const char*)As + row * 128 + ((kc * 64 + g * 16) ^ sw));
        }
        #pragma unroll
        for (int nt = 0; nt < 4; ++nt) {
            const int rk = nt * 16 + ln, sw = (rk & 7) << 4;
            #pragma unroll
            for (int kc = 0; kc < 2; ++kc)
                b2[nt][kc] = *(const short8*)((const char*)Ws + rk * 128 + ((kc * 64 + g * 16) ^ sw));
        }
        f32x4 yac[2][4];
        #pragma unroll
        for (int rs = 0; rs < 2; ++rs)
            #pragma unroll
            for (int nt = 0; nt < 4; ++nt) {
                yac[rs][nt] = (f32x4){0.f, 0.f, 0.f, 0.f};
                #pragma unroll
                for (int kc = 0; kc < 2; ++kc)
                    yac[rs][nt] = __builtin_amdgcn_mfma_f32_16x16x32_bf16(
                        a2[rs][kc], b2[nt][kc], yac[rs][nt], 0, 0, 0);
            }

        const float* __restrict__ bf2p = (which == 0) ? bfq : bfk;
        float bfv[4];
        #pragma unroll
        for (int nt = 0; nt < 4; ++nt) bfv[nt] = bf2p[nt * 16 + ln];

        ushort* __restrict__ dstF = (which == 0) ? fqd : fkd;
        float csp[4] = {0.f, 0.f, 0.f, 0.f}, csm[4] = {0.f, 0.f, 0.f, 0.f};
        #pragma unroll
        for (int rs = 0; rs < 2; ++rs)
            #pragma unroll
            for (int nt = 0; nt < 4; ++nt)
                #pragma unroll
                for (int r = 0; r < 4; ++r) {
                    const int m = m0 + 32 * w + 16 * rs + g * 4 + r;
                    const int b_ = m >> 11, s_ = m & (kS - 1);
                    const float y = yac[rs][nt][r] + bfv[nt];
                    const ushort hp = f2bf(__expf(y));
                    const ushort hm = f2bf(__expf(-y));
                    const size_t base =
                        ((size_t)(b_ * kH + hh) * kS + s_) * kF + nt * 16 + ln;
                    dstF[base] = hp;
                    dstF[base + 64] = hm;
                    if (which == 1) { csp[nt] += bf2f(hp); csm[nt] += bf2f(hm); }
                }

        if (which == 1) {
            #pragma unroll
            for (int nt = 0; nt < 4; ++nt) {
                csp[nt] += __shfl_xor(csp[nt], 16); csp[nt] += __shfl_xor(csp[nt], 32);
                csm[nt] += __shfl_xor(csm[nt], 16); csm[nt] += __shfl_xor(csm[nt], 32);
            }
            if (g == 0) {
                #pragma unroll
                for (int nt = 0; nt < 4; ++nt) {
                    zsum[w][nt * 16 + ln]      = csp[nt];
                    zsum[w][64 + nt * 16 + ln] = csm[nt];
                }
            }
            __syncthreads();
            if (t < 128) {
                const float s = zsum[0][t] + zsum[1][t] + zsum[2][t] + zsum[3][t];
                const int b_ = m0 >> 11, gr = (m0 & (kS - 1)) >> 7;
                part[((size_t)((b_ * kH + hh) * 16 + gr)) * kF + t] = s;
            }
        }
    }
}

// ---------------- softmax attention: reduced-barrier pipeline (R12) ----------------
__global__ __launch_bounds__(256) void true_attn_kernel(
    const ushort* __restrict__ q, const ushort* __restrict__ k,
    const ushort* __restrict__ vT,
    float* __restrict__ out0, float* __restrict__ out2)
{
    const int orig = blockIdx.y * 32 + blockIdx.x;        // 768 blocks
    const int swz  = (orig & 7) * 96 + (orig >> 3);
    const int bh = swz >> 5, m0 = (swz & 31) * 64;

    const int t = threadIdx.x, lane = t & 63, w = t >> 6;
    const int g = lane >> 4, ln = lane & 15;

    __shared__ __align__(16) ushort Qs[64 * 64];         // 8 KB
    __shared__ __align__(16) ushort KVs[4 * 64 * 64];    // 32 KB
    __shared__ __align__(16) ushort Ps[64 * 64];         // 8 KB

    const ushort* __restrict__ qb = q  + (size_t)bh * kS * kHD;
    const ushort* __restrict__ kb = k  + (size_t)bh * kS * kHD;
    const ushort* __restrict__ vb = vT + (size_t)bh * kHD * kS;

    stage64x64(Qs, qb + (size_t)m0 * kHD, kHD, t);
    __syncthreads();

    short8 aq[2];
    {
        const int row = 16 * w + ln, sw = (row & 7) << 4;
        #pragma unroll
        for (int kc = 0; kc < 2; ++kc)
            aq[kc] = *(const short8*)((const char*)Qs + row * 128 + ((kc * 64 + g * 16) ^ sw));
    }

    // ---- pass 1: quad-buffered K, prefetch depth 2, one barrier per iter ----
    gstage64x64(KVs, kb, kHD, w, lane);
    gstage64x64(KVs + 4096, kb + (size_t)64 * kHD, kHD, w, lane);
    float zacc[4] = {0.f, 0.f, 0.f, 0.f};
    for (int tt = 0; tt < 32; ++tt) {
        if (tt + 2 < 32) {
            gstage64x64(KVs + ((tt + 2) & 3) * 4096,
                        kb + (size_t)(tt + 2) * 64 * kHD, kHD, w, lane);
            asm volatile("s_waitcnt vmcnt(4)" ::: "memory");
        } else if (tt == 30) {
            asm volatile("s_waitcnt vmcnt(2)" ::: "memory");
        } else {
            asm volatile("s_waitcnt vmcnt(0)" ::: "memory");
        }
        __builtin_amdgcn_sched_barrier(0);
        __builtin_amdgcn_s_barrier();
        const ushort* KsC = KVs + (tt & 3) * 4096;
        #pragma unroll
        for (int nt = 0; nt < 4; ++nt) {
            f32x4 c = {0.f, 0.f, 0.f, 0.f};
            const int rk = nt * 16 + ln, sw = (rk & 7) << 4;
            #pragma unroll
            for (int kc = 0; kc < 2; ++kc) {
                short8 b = *(const short8*)((const char*)KsC + rk * 128 + ((kc * 64 + g * 16) ^ sw));
                c = __builtin_amdgcn_mfma_f32_16x16x32_bf16(aq[kc], b, c, 0, 0, 0);
            }
            #pragma unroll
            for (int r = 0; r < 4; ++r) zacc[r] += __expf(c[r] * 0.125f);
        }
    }
    float invl[4];
    #pragma unroll
    for (int r = 0; r < 4; ++r) {
        float z = zacc[r];
        z += __shfl_xor(z, 1); z += __shfl_xor(z, 2);
        z += __shfl_xor(z, 4); z += __shfl_xor(z, 8);
        invl[r] = 1.f / z;
    }
    __syncthreads();

    // ---- pass 2: probs + PV, K/V double-buffered; Ps wave-private ----
    f32x4 accv[4];
    #pragma unroll
    for (int dt = 0; dt < 4; ++dt) accv[dt] = (f32x4){0.f, 0.f, 0.f, 0.f};

    gstage64x64(KVs, kb, kHD, w, lane);
    gstage64x64(KVs + 2 * 4096, vb, kS, w, lane);
    for (int tt = 0; tt < 32; ++tt) {
        const int cur = tt & 1;
        const int n0 = tt * 64;
        if (tt + 1 < 32) {
            gstage64x64(KVs + (cur ^ 1) * 4096,
                        kb + (size_t)(tt + 1) * 64 * kHD, kHD, w, lane);
            gstage64x64(KVs + (2 + (cur ^ 1)) * 4096,
                        vb + (tt + 1) * 64, kS, w, lane);
            asm volatile("s_waitcnt vmcnt(4)" ::: "memory");
        } else {
            asm volatile("s_waitcnt vmcnt(0)" ::: "memory");
        }
        __builtin_amdgcn_sched_barrier(0);
        __builtin_amdgcn_s_barrier();

        const ushort* KsC = KVs + cur * 4096;
        const ushort* VsC = KVs + (2 + cur) * 4096;
        #pragma unroll
        for (int nt = 0; nt < 4; ++nt) {
            f32x4 c = {0.f, 0.f, 0.f, 0.f};
            const int rk = nt * 16 + ln, sw = (rk & 7) << 4;
            #pragma unroll
            for (int kc = 0; kc < 2; ++kc) {
                short8 b = *(const short8*)((const char*)KsC + rk * 128 + ((kc * 64 + g * 16) ^ sw));
                c = __builtin_amdgcn_mfma_f32_16x16x32_bf16(aq[kc], b, c, 0, 0, 0);
            }
            #pragma unroll
            for (int r = 0; r < 4; ++r) {
                const int prow = 16 * w + g * 4 + r;
                const float p = __expf(c[r] * 0.125f) * invl[r];
                out2[((size_t)bh * kS + m0 + prow) * kS + n0 + nt * 16 + ln] = p;
                const int pb = prow * 128 + ((2 * (nt * 16 + ln)) ^ ((prow & 7) << 4));
                *(ushort*)((char*)Ps + pb) = f2bf(p);
            }
        }
        asm volatile("s_waitcnt lgkmcnt(0)" ::: "memory");
        __builtin_amdgcn_sched_barrier(0);

        const int rowp = 16 * w + ln, swp = (rowp & 7) << 4;
        #pragma unroll
        for (int kc = 0; kc < 2; ++kc) {
            short8 pa = *(const short8*)((const char*)Ps + rowp * 128 + ((kc * 64 + g * 16) ^ swp));
            #pragma unroll
            for (int dt = 0; dt < 4; ++dt) {
                const int rv = dt * 16 + ln, swv = (rv & 7) << 4;
                short8 bv = *(const short8*)((const char*)VsC + rv * 128 + ((kc * 64 + g * 16) ^ swv));
                accv[dt] = __builtin_amdgcn_mfma_f32_16x16x32_bf16(pa, bv, accv[dt], 0, 0, 0);
            }
        }
        __builtin_amdgcn_sched_barrier(0);
        __builtin_amdgcn_s_barrier();
    }

    const int b_ = bh / kH, h_ = bh % kH;
    #pragma unroll
    for (int dt = 0; dt < 4; ++dt)
        #pragma unroll
        for (int r = 0; r < 4; ++r) {
            const int prow = 16 * w + g * 4 + r;
            out0[((size_t)b_ * kS + m0 + prow) * kD + h_ * kHD + dt * 16 + ln] = accv[dt][r];
        }
}

// ---------------- hedgehog predicted attention (inline fksum reduce) ----------------
__global__ __launch_bounds__(256) void pred_attn_kernel(
    const ushort* __restrict__ fq, const ushort* __restrict__ fk,
    const float* __restrict__ part, float* __restrict__ out1)
{
    const int orig = blockIdx.y * 32 + blockIdx.x;        // 768 blocks
    const int swz  = (orig & 7) * 96 + (orig >> 3);
    const int bh = swz >> 5, m0 = (swz & 31) * 64;

    const int t = threadIdx.x, lane = t & 63, w = t >> 6;
    const int g = lane >> 4, ln = lane & 15;

    __shared__ __align__(16) ushort Fq[64 * 128];         // 16 KB
    __shared__ __align__(16) ushort Fk[2 * 64 * 128];     // 32 KB dbuf
    __shared__ float fsum[128];
    __shared__ float invz[64];

    const ushort* __restrict__ fqb = fq + (size_t)bh * kS * kF;
    const ushort* __restrict__ fkb = fk + (size_t)bh * kS * kF;

    stage64x128(Fq, fqb + (size_t)m0 * kF, t);
    if (t < 128) {
        float s = 0.f;
        #pragma unroll
        for (int gg = 0; gg < 16; ++gg) s += part[((size_t)bh * 16 + gg) * kF + t];
        fsum[t] = s;
    }
    __syncthreads();

    short8 a[4];
    {
        const int row = 16 * w + ln, sw = (row & 7) << 4;
        #pragma unroll
        for (int kc = 0; kc < 4; ++kc)
            a[kc] = *(const short8*)((const char*)Fq + row * 256 + ((kc * 64 + g * 16) ^ sw));
    }

    float den = 0.f;
    #pragma unroll
    for (int kc = 0; kc < 4; ++kc)
        #pragma unroll
        for (int j = 0; j < 8; ++j)
            den += bf2f((ushort)a[kc][j]) * fsum[kc * 32 + g * 8 + j];
    den += __shfl_xor(den, 16);
    den += __shfl_xor(den, 32);
    if (g == 0) invz[16 * w + ln] = 1.f / den;
    __syncthreads();
    float invl[4];
    #pragma unroll
    for (int r = 0; r < 4; ++r) invl[r] = invz[16 * w + g * 4 + r];

    gstage64x128(Fk, fkb, w, lane);
    for (int tt = 0; tt < 32; ++tt) {
        const int cur = tt & 1;
        const int n0 = tt * 64;
        if (tt + 1 < 32) {
            gstage64x128(Fk + (cur ^ 1) * 8192, fkb + (size_t)(tt + 1) * 64 * kF, w, lane);
            asm volatile("s_waitcnt vmcnt(4)" ::: "memory");
        } else {
            asm volatile("s_waitcnt vmcnt(0)" ::: "memory");
        }
        __builtin_amdgcn_sched_barrier(0);
        __builtin_amdgcn_s_barrier();

        const ushort* FkC = Fk + cur * 8192;
        #pragma unroll
        for (int nt = 0; nt < 4; ++nt) {
            f32x4 c = {0.f, 0.f, 0.f, 0.f};
            const int rk = nt * 16 + ln, sw = (rk & 7) << 4;
            #pragma unroll
            for (int kc = 0; kc < 4; ++kc) {
                short8 b = *(const short8*)((const char*)FkC + rk * 256 + ((kc * 64 + g * 16) ^ sw));
                c = __builtin_amdgcn_mfma_f32_16x16x32_bf16(a[kc], b, c, 0, 0, 0);
            }
            #pragma unroll
            for (int r = 0; r < 4; ++r)
                out1[((size_t)bh * kS + m0 + 16 * w + g * 4 + r) * kS + n0 + nt * 16 + ln] =
                    c[r] * invl[r];
        }
        __builtin_amdgcn_sched_barrier(0);
        __builtin_amdgcn_s_barrier();
    }
}

}  // namespace

extern "C" void kernel_launch(void* const* d_in, const int* in_sizes, int n_in,
                              void* d_out, int out_size, void* d_ws, size_t ws_size,
                              hipStream_t stream)
{
    (void)in_sizes; (void)n_in; (void)out_size; (void)ws_size;

    const float* hidden = (const float*)d_in[0];
    const float* Wq = (const float*)d_in[1];
    const float* bq = (const float*)d_in[2];
    const float* Wk = (const float*)d_in[3];
    const float* bk = (const float*)d_in[4];
    const float* Wv = (const float*)d_in[5];
    const float* bv = (const float*)d_in[6];
    const float* Wfq = (const float*)d_in[7];
    const float* bfq = (const float*)d_in[8];
    const float* Wfk = (const float*)d_in[9];
    const float* bfk = (const float*)d_in[10];

    float* out = (float*)d_out;
    float* out0 = out;                                   // outputs   [B,S,D]
    float* out1 = out0 + (size_t)kB * kS * kD;           // pred_attns[B,H,S,S]
    float* out2 = out1 + (size_t)kBH * kS * kS;          // true_attns[B,H,S,S]

    float* part = (float*)d_ws;                          // [kBH*16*kF]
    ushort* hb  = (ushort*)(part + (size_t)kBH * 16 * kF);   // hidden bf16
    ushort* Wqb = hb  + (size_t)kB * kS * kD;
    ushort* Wkb = Wqb + (size_t)kD * kD;
    ushort* Wvb = Wkb + (size_t)kD * kD;
    ushort* qw  = Wvb + (size_t)kD * kD;
    ushort* kw  = qw  + (size_t)kBH * kS * kHD;
    ushort* vTw = kw  + (size_t)kBH * kS * kHD;
    ushort* fqw = vTw + (size_t)kBH * kS * kHD;
    ushort* fkw = fqw + (size_t)kBH * kS * kF;

    cast_kernel<<<dim3(512, 4), 256, 0, stream>>>(
        hidden, Wq, Wk, Wv, hb, Wqb, Wkb, Wvb);
    qkv_mfma_kernel<<<dim3(kB * kS / 128, kD / 64, 3), 256, 0, stream>>>(
        hb, Wqb, Wkb, Wvb, bq, bk, bv,
        Wfq, bfq, Wfk, bfk,
        qw, kw, vTw, fqw, fkw, part);
    true_attn_kernel<<<dim3(kS / 64, kBH), 256, 0, stream>>>(qw, kw, vTw, out0, out2);
    pred_attn_kernel<<<dim3(kS / 64, kBH), 256, 0, stream>>>(fqw, fkw, part, out1);
}

// Round 14
// 300.958 us; speedup vs baseline: 1.1090x; 1.0452x over previous
//
#include <hip/hip_runtime.h>
#include <math.h>

namespace {

constexpr int kB = 2, kS = 2048, kD = 768, kH = 12, kHD = 64, kF = 128, kBH = kB * kH;

typedef __attribute__((ext_vector_type(8))) short short8;
typedef __attribute__((ext_vector_type(4))) short short4v;
typedef __attribute__((ext_vector_type(4))) float f32x4;

__device__ __forceinline__ ushort f2bf(float x) {
    union { float f; unsigned u; } v; v.f = x;
    return (ushort)((v.u + 0x7fffu + ((v.u >> 16) & 1u)) >> 16);
}
__device__ __forceinline__ float bf2f(ushort u) {
    union { unsigned u; float f; } v; v.u = ((unsigned)u) << 16; return v.f;
}

__device__ __forceinline__ void gload16(const ushort* g, void* lds) {
    __builtin_amdgcn_global_load_lds(
        (const __attribute__((address_space(1))) void*)g,
        (__attribute__((address_space(3))) void*)lds, 16, 0, 0);
}

// ---- 4-wave staging helpers (qkv kernel, 256 threads) ----
__device__ __forceinline__ void gstage64x64(ushort* ldsBase, const ushort* g,
                                            size_t strideElems, int w, int lane) {
    #pragma unroll
    for (int j = 0; j < 2; ++j) {
        const int row = 16 * w + 8 * j + (lane >> 3);
        const int chunk = lane & 7;
        const ushort* gp = g + (size_t)row * strideElems + ((chunk ^ (row & 7)) * 8);
        void* lp = (char*)ldsBase + (16 * w + 8 * j) * 128;
        gload16(gp, lp);
    }
}
__device__ __forceinline__ void gstageA128(ushort* ldsBase, const ushort* g,
                                           size_t strideElems, int w, int lane) {
    #pragma unroll
    for (int j = 0; j < 4; ++j) {
        const int row = 32 * w + 8 * j + (lane >> 3);
        const int chunk = lane & 7;
        const ushort* gp = g + (size_t)row * strideElems + ((chunk ^ (row & 7)) * 8);
        void* lp = (char*)ldsBase + (32 * w + 8 * j) * 128;
        gload16(gp, lp);
    }
}

// ---- 8-wave staging helpers (attn kernels, 512 threads) ----
// 64x64 tile, rows 128B: wave w stages rows [8w, 8w+8), ONE gload16/wave.
__device__ __forceinline__ void gstage8x64(ushort* ldsBase, const ushort* g,
                                           size_t strideElems, int w, int lane) {
    const int row = 8 * w + (lane >> 3);
    const int chunk = lane & 7;
    gload16(g + (size_t)row * strideElems + ((chunk ^ (row & 7)) * 8),
            (char*)ldsBase + 8 * w * 128);
}
// 64x128 tile, rows 256B: wave w stages rows [8w, 8w+8), TWO gload16/wave.
__device__ __forceinline__ void gstage8x128(ushort* ldsBase, const ushort* g,
                                            int w, int lane) {
    #pragma unroll
    for (int j = 0; j < 2; ++j) {
        const int row = 8 * w + 4 * j + (lane >> 4);
        const int chunk = lane & 15;
        gload16(g + (size_t)row * kF + ((chunk ^ (row & 7)) * 8),
                (char*)ldsBase + (8 * w + 4 * j) * 256);
    }
}

// ---------------- fp32 -> bf16 casts ----------------
__global__ __launch_bounds__(256) void cast_kernel(
    const float* __restrict__ s0, const float* __restrict__ s1,
    const float* __restrict__ s2, const float* __restrict__ s3,
    ushort* __restrict__ d0, ushort* __restrict__ d1,
    ushort* __restrict__ d2, ushort* __restrict__ d3)
{
    const int seg = blockIdx.y;
    const float* src = seg == 0 ? s0 : seg == 1 ? s1 : seg == 2 ? s2 : s3;
    ushort* dst      = seg == 0 ? d0 : seg == 1 ? d1 : seg == 2 ? d2 : d3;
    const int n4 = (seg == 0 ? kB * kS * kD : kD * kD) / 4;
    for (int i = blockIdx.x * 256 + threadIdx.x; i < n4; i += gridDim.x * 256) {
        float4 v = *(const float4*)&src[(size_t)i * 4];
        short4v o;
        o[0] = (short)f2bf(v.x); o[1] = (short)f2bf(v.y);
        o[2] = (short)f2bf(v.z); o[3] = (short)f2bf(v.w);
        *(short4v*)&dst[(size_t)i * 4] = o;
    }
}

// ---------------- QKV projection + fused hedgehog feature map (R13) ----------------
__global__ __launch_bounds__(256) void qkv_mfma_kernel(
    const ushort* __restrict__ hb,
    const ushort* __restrict__ Wqb, const ushort* __restrict__ Wkb,
    const ushort* __restrict__ Wvb,
    const float* __restrict__ bq, const float* __restrict__ bk,
    const float* __restrict__ bv,
    const float* __restrict__ Wfq, const float* __restrict__ bfq,
    const float* __restrict__ Wfk, const float* __restrict__ bfk,
    ushort* __restrict__ qd, ushort* __restrict__ kd, ushort* __restrict__ vTd,
    ushort* __restrict__ fqd, ushort* __restrict__ fkd,
    float* __restrict__ part)
{
    const int which = blockIdx.z;
    const ushort* __restrict__ Wb  = which == 0 ? Wqb : which == 1 ? Wkb : Wvb;
    const float* __restrict__ bias = which == 0 ? bq : which == 1 ? bk : bv;

    const int m0 = blockIdx.x * 128;
    const int n0 = blockIdx.y * 64;
    const int t = threadIdx.x, lane = t & 63, w = t >> 6;
    const int g = lane >> 4, ln = lane & 15;

    __shared__ __align__(16) ushort As[128 * 64];
    __shared__ __align__(16) ushort Bs[64 * 64];
    __shared__ __align__(16) ushort Ws[64 * 64];
    __shared__ float zsum[4][128];

    if (which < 2) {
        const float* __restrict__ Wf = (which == 0) ? Wfq : Wfk;
        const int row = t >> 2, ce = (t & 3) * 16;
        ushort tmp[16];
        #pragma unroll
        for (int c = 0; c < 16; c += 4) {
            float4 u = *(const float4*)&Wf[(size_t)row * 64 + ce + c];
            tmp[c + 0] = f2bf(u.x); tmp[c + 1] = f2bf(u.y);
            tmp[c + 2] = f2bf(u.z); tmp[c + 3] = f2bf(u.w);
        }
        const int sw = (row & 7) << 4;
        *(uint4*)((char*)Ws + row * 128 + ((ce * 2) ^ sw)) = *(uint4*)&tmp[0];
        *(uint4*)((char*)Ws + row * 128 + ((ce * 2 + 16) ^ sw)) = *(uint4*)&tmp[8];
    }

    f32x4 acc[2][4];
    #pragma unroll
    for (int rs = 0; rs < 2; ++rs)
        #pragma unroll
        for (int nt = 0; nt < 4; ++nt) acc[rs][nt] = (f32x4){0.f, 0.f, 0.f, 0.f};

    for (int k0 = 0; k0 < kD; k0 += 64) {
        gstageA128(As, hb + (size_t)m0 * kD + k0, kD, w, lane);
        gstage64x64(Bs, Wb + (size_t)n0 * kD + k0, kD, w, lane);
        asm volatile("s_waitcnt vmcnt(0)" ::: "memory");
        __builtin_amdgcn_sched_barrier(0);
        __builtin_amdgcn_s_barrier();

        short8 a[2][2], b[4][2];
        #pragma unroll
        for (int rs = 0; rs < 2; ++rs) {
            const int row = 32 * w + 16 * rs + ln, sw = (row & 7) << 4;
            #pragma unroll
            for (int kc = 0; kc < 2; ++kc)
                a[rs][kc] = *(const short8*)((const char*)As + row * 128 + ((kc * 64 + g * 16) ^ sw));
        }
        #pragma unroll
        for (int nt = 0; nt < 4; ++nt) {
            const int rk = nt * 16 + ln, sw = (rk & 7) << 4;
            #pragma unroll
            for (int kc = 0; kc < 2; ++kc)
                b[nt][kc] = *(const short8*)((const char*)Bs + rk * 128 + ((kc * 64 + g * 16) ^ sw));
        }
        #pragma unroll
        for (int rs = 0; rs < 2; ++rs)
            #pragma unroll
            for (int nt = 0; nt < 4; ++nt)
                #pragma unroll
                for (int kc = 0; kc < 2; ++kc)
                    acc[rs][nt] = __builtin_amdgcn_mfma_f32_16x16x32_bf16(
                        a[rs][kc], b[nt][kc], acc[rs][nt], 0, 0, 0);
        asm volatile("s_waitcnt lgkmcnt(0)" ::: "memory");
        __builtin_amdgcn_sched_barrier(0);
        __builtin_amdgcn_s_barrier();
    }

    const int hh = n0 >> 6;
    float bvn[4];
    #pragma unroll
    for (int nt = 0; nt < 4; ++nt) bvn[nt] = bias[n0 + nt * 16 + ln];

    if (which < 2) {
        ushort* __restrict__ dst = (which == 0) ? qd : kd;
        #pragma unroll
        for (int rs = 0; rs < 2; ++rs)
            #pragma unroll
            for (int nt = 0; nt < 4; ++nt)
                #pragma unroll
                for (int r = 0; r < 4; ++r) {
                    const int m = m0 + 32 * w + 16 * rs + g * 4 + r;
                    const int b_ = m >> 11, s_ = m & (kS - 1);
                    dst[((size_t)(b_ * kH + hh) * kS + s_) * kHD + nt * 16 + ln] =
                        f2bf(acc[rs][nt][r] + bvn[nt]);
                }
    } else {
        #pragma unroll
        for (int rs = 0; rs < 2; ++rs)
            #pragma unroll
            for (int nt = 0; nt < 4; ++nt) {
                const int m = m0 + 32 * w + 16 * rs + g * 4;
                const int b_ = m >> 11, s_ = m & (kS - 1);
                const int d = nt * 16 + ln;
                short4v o;
                #pragma unroll
                for (int r = 0; r < 4; ++r) o[r] = (short)f2bf(acc[rs][nt][r] + bvn[nt]);
                *(short4v*)&vTd[((size_t)(b_ * kH + hh) * kHD + d) * kS + s_] = o;
            }
    }

    if (which < 2) {
        __syncthreads();
        #pragma unroll
        for (int rs = 0; rs < 2; ++rs)
            #pragma unroll
            for (int nt = 0; nt < 4; ++nt)
                #pragma unroll
                for (int r = 0; r < 4; ++r) {
                    const int bm = 32 * w + 16 * rs + g * 4 + r;
                    const int e = nt * 16 + ln;
                    *(ushort*)((char*)As + bm * 128 + ((2 * e) ^ ((bm & 7) << 4))) =
                        f2bf(acc[rs][nt][r] + bvn[nt]);
                }
        __syncthreads();

        short8 a2[2][2], b2[4][2];
        #pragma unroll
        for (int rs = 0; rs < 2; ++rs) {
            const int row = 32 * w + 16 * rs + ln, sw = (row & 7) << 4;
            #pragma unroll
            for (int kc = 0; kc < 2; ++kc)
                a2[rs][kc] = *(const short8*)((const char*)As + row * 128 + ((kc * 64 + g * 16) ^ sw));
        }
        #pragma unroll
        for (int nt = 0; nt < 4; ++nt) {
            const int rk = nt * 16 + ln, sw = (rk & 7) << 4;
            #pragma unroll
            for (int kc = 0; kc < 2; ++kc)
                b2[nt][kc] = *(const short8*)((const char*)Ws + rk * 128 + ((kc * 64 + g * 16) ^ sw));
        }
        f32x4 yac[2][4];
        #pragma unroll
        for (int rs = 0; rs < 2; ++rs)
            #pragma unroll
            for (int nt = 0; nt < 4; ++nt) {
                yac[rs][nt] = (f32x4){0.f, 0.f, 0.f, 0.f};
                #pragma unroll
                for (int kc = 0; kc < 2; ++kc)
                    yac[rs][nt] = __builtin_amdgcn_mfma_f32_16x16x32_bf16(
                        a2[rs][kc], b2[nt][kc], yac[rs][nt], 0, 0, 0);
            }

        const float* __restrict__ bf2p = (which == 0) ? bfq : bfk;
        float bfv[4];
        #pragma unroll
        for (int nt = 0; nt < 4; ++nt) bfv[nt] = bf2p[nt * 16 + ln];

        ushort* __restrict__ dstF = (which == 0) ? fqd : fkd;
        float csp[4] = {0.f, 0.f, 0.f, 0.f}, csm[4] = {0.f, 0.f, 0.f, 0.f};
        #pragma unroll
        for (int rs = 0; rs < 2; ++rs)
            #pragma unroll
            for (int nt = 0; nt < 4; ++nt)
                #pragma unroll
                for (int r = 0; r < 4; ++r) {
                    const int m = m0 + 32 * w + 16 * rs + g * 4 + r;
                    const int b_ = m >> 11, s_ = m & (kS - 1);
                    const float y = yac[rs][nt][r] + bfv[nt];
                    const ushort hp = f2bf(__expf(y));
                    const ushort hm = f2bf(__expf(-y));
                    const size_t base =
                        ((size_t)(b_ * kH + hh) * kS + s_) * kF + nt * 16 + ln;
                    dstF[base] = hp;
                    dstF[base + 64] = hm;
                    if (which == 1) { csp[nt] += bf2f(hp); csm[nt] += bf2f(hm); }
                }

        if (which == 1) {
            #pragma unroll
            for (int nt = 0; nt < 4; ++nt) {
                csp[nt] += __shfl_xor(csp[nt], 16); csp[nt] += __shfl_xor(csp[nt], 32);
                csm[nt] += __shfl_xor(csm[nt], 16); csm[nt] += __shfl_xor(csm[nt], 32);
            }
            if (g == 0) {
                #pragma unroll
                for (int nt = 0; nt < 4; ++nt) {
                    zsum[w][nt * 16 + ln]      = csp[nt];
                    zsum[w][64 + nt * 16 + ln] = csm[nt];
                }
            }
            __syncthreads();
            if (t < 128) {
                const float s = zsum[0][t] + zsum[1][t] + zsum[2][t] + zsum[3][t];
                const int b_ = m0 >> 11, gr = (m0 & (kS - 1)) >> 7;
                part[((size_t)((b_ * kH + hh) * 16 + gr)) * kF + t] = s;
            }
        }
    }
}

// ---------------- softmax attention: 8-wave (512 threads), 6 waves/SIMD ----------------
// wave w = (wr = w&3: row group, wc = w>>2: col half). Per iter per wave: 2-nt cluster.
__global__ __launch_bounds__(512) void true_attn_kernel(
    const ushort* __restrict__ q, const ushort* __restrict__ k,
    const ushort* __restrict__ vT,
    float* __restrict__ out0, float* __restrict__ out2)
{
    const int orig = blockIdx.y * 32 + blockIdx.x;        // 768 blocks
    const int swz  = (orig & 7) * 96 + (orig >> 3);
    const int bh = swz >> 5, m0 = (swz & 31) * 64;

    const int t = threadIdx.x, lane = t & 63, w = t >> 6;  // w in [0,8)
    const int g = lane >> 4, ln = lane & 15;
    const int wr = w & 3, wc = w >> 2;

    __shared__ __align__(16) ushort Qs[64 * 64];          // 8 KB
    __shared__ __align__(16) ushort KVs[4 * 64 * 64];     // 32 KB
    __shared__ __align__(16) ushort Ps[64 * 64];          // 8 KB
    __shared__ float zl[8][16];

    const ushort* __restrict__ qb = q  + (size_t)bh * kS * kHD;
    const ushort* __restrict__ kb = k  + (size_t)bh * kS * kHD;
    const ushort* __restrict__ vb = vT + (size_t)bh * kHD * kS;

    {   // stage Q: 512 threads, one uint4 each
        const int row = t >> 3, ce = (t & 7) * 8;
        uint4 u = *(const uint4*)(qb + (size_t)(m0 + row) * kHD + ce);
        *(uint4*)((char*)Qs + row * 128 + ((ce * 2) ^ ((row & 7) << 4))) = u;
    }
    __syncthreads();

    short8 aq[2];
    {
        const int row = 16 * wr + ln, sw = (row & 7) << 4;
        #pragma unroll
        for (int kc = 0; kc < 2; ++kc)
            aq[kc] = *(const short8*)((const char*)Qs + row * 128 + ((kc * 64 + g * 16) ^ sw));
    }

    // ---- pass 1: quad-buffered K, depth 2, one barrier/iter ----
    gstage8x64(KVs, kb, kHD, w, lane);
    gstage8x64(KVs + 4096, kb + (size_t)64 * kHD, kHD, w, lane);
    float zacc[4] = {0.f, 0.f, 0.f, 0.f};
    for (int tt = 0; tt < 32; ++tt) {
        if (tt + 2 < 32) {
            gstage8x64(KVs + ((tt + 2) & 3) * 4096,
                       kb + (size_t)(tt + 2) * 64 * kHD, kHD, w, lane);
            asm volatile("s_waitcnt vmcnt(2)" ::: "memory");
        } else if (tt == 30) {
            asm volatile("s_waitcnt vmcnt(1)" ::: "memory");
        } else {
            asm volatile("s_waitcnt vmcnt(0)" ::: "memory");
        }
        __builtin_amdgcn_sched_barrier(0);
        __builtin_amdgcn_s_barrier();
        const ushort* KsC = KVs + (tt & 3) * 4096;
        #pragma unroll
        for (int h2 = 0; h2 < 2; ++h2) {
            const int nt = 2 * wc + h2;
            f32x4 c = {0.f, 0.f, 0.f, 0.f};
            const int rk = nt * 16 + ln, sw = (rk & 7) << 4;
            #pragma unroll
            for (int kc = 0; kc < 2; ++kc) {
                short8 b = *(const short8*)((const char*)KsC + rk * 128 + ((kc * 64 + g * 16) ^ sw));
                c = __builtin_amdgcn_mfma_f32_16x16x32_bf16(aq[kc], b, c, 0, 0, 0);
            }
            #pragma unroll
            for (int r = 0; r < 4; ++r) zacc[r] += __expf(c[r] * 0.125f);
        }
    }
    // reduce cols within wave (over ln), then across the wave pair via LDS
    #pragma unroll
    for (int r = 0; r < 4; ++r) {
        float z = zacc[r];
        z += __shfl_xor(z, 1); z += __shfl_xor(z, 2);
        z += __shfl_xor(z, 4); z += __shfl_xor(z, 8);
        zacc[r] = z;
    }
    if (ln == 0) {
        #pragma unroll
        for (int r = 0; r < 4; ++r) zl[w][g * 4 + r] = zacc[r];
    }
    __syncthreads();
    float invl[4];
    #pragma unroll
    for (int r = 0; r < 4; ++r)
        invl[r] = 1.f / (zl[wr][g * 4 + r] + zl[4 + wr][g * 4 + r]);

    // ---- pass 2: probs + PV, K/V double-buffered ----
    f32x4 accv[2];
    accv[0] = (f32x4){0.f, 0.f, 0.f, 0.f};
    accv[1] = (f32x4){0.f, 0.f, 0.f, 0.f};

    gstage8x64(KVs, kb, kHD, w, lane);
    gstage8x64(KVs + 2 * 4096, vb, kS, w, lane);
    for (int tt = 0; tt < 32; ++tt) {
        const int cur = tt & 1;
        const int n0 = tt * 64;
        if (tt + 1 < 32) {
            gstage8x64(KVs + (cur ^ 1) * 4096,
                       kb + (size_t)(tt + 1) * 64 * kHD, kHD, w, lane);
            gstage8x64(KVs + (2 + (cur ^ 1)) * 4096,
                       vb + (tt + 1) * 64, kS, w, lane);
            asm volatile("s_waitcnt vmcnt(2)" ::: "memory");
        } else {
            asm volatile("s_waitcnt vmcnt(0)" ::: "memory");
        }
        __builtin_amdgcn_sched_barrier(0);
        __builtin_amdgcn_s_barrier();

        const ushort* KsC = KVs + cur * 4096;
        const ushort* VsC = KVs + (2 + cur) * 4096;
        #pragma unroll
        for (int h2 = 0; h2 < 2; ++h2) {
            const int nt = 2 * wc + h2;
            f32x4 c = {0.f, 0.f, 0.f, 0.f};
            const int rk = nt * 16 + ln, sw = (rk & 7) << 4;
            #pragma unroll
            for (int kc = 0; kc < 2; ++kc) {
                short8 b = *(const short8*)((const char*)KsC + rk * 128 + ((kc * 64 + g * 16) ^ sw));
                c = __builtin_amdgcn_mfma_f32_16x16x32_bf16(aq[kc], b, c, 0, 0, 0);
            }
            #pragma unroll
            for (int r = 0; r < 4; ++r) {
                const int prow = 16 * wr + g * 4 + r;
                const float p = __expf(c[r] * 0.125f) * invl[r];
                out2[((size_t)bh * kS + m0 + prow) * kS + n0 + nt * 16 + ln] = p;
                const int pb = prow * 128 + ((2 * (nt * 16 + ln)) ^ ((prow & 7) << 4));
                *(ushort*)((char*)Ps + pb) = f2bf(p);
            }
        }
        asm volatile("s_waitcnt lgkmcnt(0)" ::: "memory");
        __builtin_amdgcn_sched_barrier(0);
        __builtin_amdgcn_s_barrier();   // P rows shared across the wave pair

        const int rowp = 16 * wr + ln, swp = (rowp & 7) << 4;
        #pragma unroll
        for (int kc = 0; kc < 2; ++kc) {
            short8 pa = *(const short8*)((const char*)Ps + rowp * 128 + ((kc * 64 + g * 16) ^ swp));
            #pragma unroll
            for (int d2 = 0; d2 < 2; ++d2) {
                const int dt = 2 * wc + d2;
                const int rv = dt * 16 + ln, swv = (rv & 7) << 4;
                short8 bv = *(const short8*)((const char*)VsC + rv * 128 + ((kc * 64 + g * 16) ^ swv));
                accv[d2] = __builtin_amdgcn_mfma_f32_16x16x32_bf16(pa, bv, accv[d2], 0, 0, 0);
            }
        }
        __builtin_amdgcn_sched_barrier(0);
        __builtin_amdgcn_s_barrier();
    }

    const int b_ = bh / kH, h_ = bh % kH;
    #pragma unroll
    for (int d2 = 0; d2 < 2; ++d2)
        #pragma unroll
        for (int r = 0; r < 4; ++r) {
            const int prow = 16 * wr + g * 4 + r;
            const int dt = 2 * wc + d2;
            out0[((size_t)b_ * kS + m0 + prow) * kD + h_ * kHD + dt * 16 + ln] = accv[d2][r];
        }
}

// ---------------- hedgehog predicted attention: 8-wave (512 threads) ----------------
__global__ __launch_bounds__(512) void pred_attn_kernel(
    const ushort* __restrict__ fq, const ushort* __restrict__ fk,
    const float* __restrict__ part, float* __restrict__ out1)
{
    const int orig = blockIdx.y * 32 + blockIdx.x;        // 768 blocks
    const int swz  = (orig & 7) * 96 + (orig >> 3);
    const int bh = swz >> 5, m0 = (swz & 31) * 64;

    const int t = threadIdx.x, lane = t & 63, w = t >> 6;  // w in [0,8)
    const int g = lane >> 4, ln = lane & 15;
    const int wr = w & 3, wc = w >> 2;

    __shared__ __align__(16) ushort Fq[64 * 128];          // 16 KB
    __shared__ __align__(16) ushort Fk[2 * 64 * 128];      // 32 KB dbuf
    __shared__ float fsum[128];
    __shared__ float invz[64];

    const ushort* __restrict__ fqb = fq + (size_t)bh * kS * kF;
    const ushort* __restrict__ fkb = fk + (size_t)bh * kS * kF;

    {   // stage Fq: 512 threads, two uint4 each
        const int row = t >> 3, ce = (t & 7) * 16;
        const ushort* s = fqb + (size_t)(m0 + row) * kF + ce;
        const int sw = (row & 7) << 4;
        *(uint4*)((char*)Fq + row * 256 + ((ce * 2) ^ sw)) = *(const uint4*)s;
        *(uint4*)((char*)Fq + row * 256 + ((ce * 2 + 16) ^ sw)) = *(const uint4*)(s + 8);
    }
    if (t < 128) {
        float s = 0.f;
        #pragma unroll
        for (int gg = 0; gg < 16; ++gg) s += part[((size_t)bh * 16 + gg) * kF + t];
        fsum[t] = s;
    }
    __syncthreads();

    short8 a[4];
    {
        const int row = 16 * wr + ln, sw = (row & 7) << 4;
        #pragma unroll
        for (int kc = 0; kc < 4; ++kc)
            a[kc] = *(const short8*)((const char*)Fq + row * 256 + ((kc * 64 + g * 16) ^ sw));
    }

    float den = 0.f;
    #pragma unroll
    for (int kc = 0; kc < 4; ++kc)
        #pragma unroll
        for (int j = 0; j < 8; ++j)
            den += bf2f((ushort)a[kc][j]) * fsum[kc * 32 + g * 8 + j];
    den += __shfl_xor(den, 16);
    den += __shfl_xor(den, 32);
    if (g == 0) invz[16 * wr + ln] = 1.f / den;   // wave pair writes identical values
    __syncthreads();
    float invl[4];
    #pragma unroll
    for (int r = 0; r < 4; ++r) invl[r] = invz[16 * wr + g * 4 + r];

    gstage8x128(Fk, fkb, w, lane);
    for (int tt = 0; tt < 32; ++tt) {
        const int cur = tt & 1;
        const int n0 = tt * 64;
        if (tt + 1 < 32) {
            gstage8x128(Fk + (cur ^ 1) * 8192, fkb + (size_t)(tt + 1) * 64 * kF, w, lane);
            asm volatile("s_waitcnt vmcnt(2)" ::: "memory");
        } else {
            asm volatile("s_waitcnt vmcnt(0)" ::: "memory");
        }
        __builtin_amdgcn_sched_barrier(0);
        __builtin_amdgcn_s_barrier();

        const ushort* FkC = Fk + cur * 8192;
        #pragma unroll
        for (int h2 = 0; h2 < 2; ++h2) {
            const int nt = 2 * wc + h2;
            f32x4 c = {0.f, 0.f, 0.f, 0.f};
            const int rk = nt * 16 + ln, sw = (rk & 7) << 4;
            #pragma unroll
            for (int kc = 0; kc < 4; ++kc) {
                short8 b = *(const short8*)((const char*)FkC + rk * 256 + ((kc * 64 + g * 16) ^ sw));
                c = __builtin_amdgcn_mfma_f32_16x16x32_bf16(a[kc], b, c, 0, 0, 0);
            }
            #pragma unroll
            for (int r = 0; r < 4; ++r)
                out1[((size_t)bh * kS + m0 + 16 * wr + g * 4 + r) * kS + n0 + nt * 16 + ln] =
                    c[r] * invl[r];
        }
        __builtin_amdgcn_sched_barrier(0);
        __builtin_amdgcn_s_barrier();
    }
}

}  // namespace

extern "C" void kernel_launch(void* const* d_in, const int* in_sizes, int n_in,
                              void* d_out, int out_size, void* d_ws, size_t ws_size,
                              hipStream_t stream)
{
    (void)in_sizes; (void)n_in; (void)out_size; (void)ws_size;

    const float* hidden = (const float*)d_in[0];
    const float* Wq = (const float*)d_in[1];
    const float* bq = (const float*)d_in[2];
    const float* Wk = (const float*)d_in[3];
    const float* bk = (const float*)d_in[4];
    const float* Wv = (const float*)d_in[5];
    const float* bv = (const float*)d_in[6];
    const float* Wfq = (const float*)d_in[7];
    const float* bfq = (const float*)d_in[8];
    const float* Wfk = (const float*)d_in[9];
    const float* bfk = (const float*)d_in[10];

    float* out = (float*)d_out;
    float* out0 = out;                                   // outputs   [B,S,D]
    float* out1 = out0 + (size_t)kB * kS * kD;           // pred_attns[B,H,S,S]
    float* out2 = out1 + (size_t)kBH * kS * kS;          // true_attns[B,H,S,S]

    float* part = (float*)d_ws;                          // [kBH*16*kF]
    ushort* hb  = (ushort*)(part + (size_t)kBH * 16 * kF);   // hidden bf16
    ushort* Wqb = hb  + (size_t)kB * kS * kD;
    ushort* Wkb = Wqb + (size_t)kD * kD;
    ushort* Wvb = Wkb + (size_t)kD * kD;
    ushort* qw  = Wvb + (size_t)kD * kD;
    ushort* kw  = qw  + (size_t)kBH * kS * kHD;
    ushort* vTw = kw  + (size_t)kBH * kS * kHD;
    ushort* fqw = vTw + (size_t)kBH * kS * kHD;
    ushort* fkw = fqw + (size_t)kBH * kS * kF;

    cast_kernel<<<dim3(512, 4), 256, 0, stream>>>(
        hidden, Wq, Wk, Wv, hb, Wqb, Wkb, Wvb);
    qkv_mfma_kernel<<<dim3(kB * kS / 128, kD / 64, 3), 256, 0, stream>>>(
        hb, Wqb, Wkb, Wvb, bq, bk, bv,
        Wfq, bfq, Wfk, bfk,
        qw, kw, vTw, fqw, fkw, part);
    true_attn_kernel<<<dim3(kS / 64, kBH), 512, 0, stream>>>(qw, kw, vTw, out0, out2);
    pred_attn_kernel<<<dim3(kS / 64, kBH), 512, 0, stream>>>(fqw, fkw, part, out1);
}

// Round 15
// 290.985 us; speedup vs baseline: 1.1470x; 1.0343x over previous
//
#include <hip/hip_runtime.h>
#include <math.h>

namespace {

constexpr int kB = 2, kS = 2048, kD = 768, kH = 12, kHD = 64, kF = 128, kBH = kB * kH;

typedef __attribute__((ext_vector_type(8))) short short8;
typedef __attribute__((ext_vector_type(4))) short short4v;
typedef __attribute__((ext_vector_type(4))) float f32x4;

__device__ __forceinline__ ushort f2bf(float x) {
    union { float f; unsigned u; } v; v.f = x;
    return (ushort)((v.u + 0x7fffu + ((v.u >> 16) & 1u)) >> 16);
}
__device__ __forceinline__ float bf2f(ushort u) {
    union { unsigned u; float f; } v; v.u = ((unsigned)u) << 16; return v.f;
}

__device__ __forceinline__ void gload16(const ushort* g, void* lds) {
    __builtin_amdgcn_global_load_lds(
        (const __attribute__((address_space(1))) void*)g,
        (__attribute__((address_space(3))) void*)lds, 16, 0, 0);
}

// ---- 4-wave staging helpers (qkv kernel, 256 threads) ----
__device__ __forceinline__ void gstage64x64(ushort* ldsBase, const ushort* g,
                                            size_t strideElems, int w, int lane) {
    #pragma unroll
    for (int j = 0; j < 2; ++j) {
        const int row = 16 * w + 8 * j + (lane >> 3);
        const int chunk = lane & 7;
        const ushort* gp = g + (size_t)row * strideElems + ((chunk ^ (row & 7)) * 8);
        void* lp = (char*)ldsBase + (16 * w + 8 * j) * 128;
        gload16(gp, lp);
    }
}
__device__ __forceinline__ void gstageA128(ushort* ldsBase, const ushort* g,
                                           size_t strideElems, int w, int lane) {
    #pragma unroll
    for (int j = 0; j < 4; ++j) {
        const int row = 32 * w + 8 * j + (lane >> 3);
        const int chunk = lane & 7;
        const ushort* gp = g + (size_t)row * strideElems + ((chunk ^ (row & 7)) * 8);
        void* lp = (char*)ldsBase + (32 * w + 8 * j) * 128;
        gload16(gp, lp);
    }
}

// ---- 8-wave staging helpers (attn kernels, 512 threads) ----
__device__ __forceinline__ void gstage8x64(ushort* ldsBase, const ushort* g,
                                           size_t strideElems, int w, int lane) {
    const int row = 8 * w + (lane >> 3);
    const int chunk = lane & 7;
    gload16(g + (size_t)row * strideElems + ((chunk ^ (row & 7)) * 8),
            (char*)ldsBase + 8 * w * 128);
}
__device__ __forceinline__ void gstage8x128(ushort* ldsBase, const ushort* g,
                                            int w, int lane) {
    #pragma unroll
    for (int j = 0; j < 2; ++j) {
        const int row = 8 * w + 4 * j + (lane >> 4);
        const int chunk = lane & 15;
        gload16(g + (size_t)row * kF + ((chunk ^ (row & 7)) * 8),
                (char*)ldsBase + (8 * w + 4 * j) * 256);
    }
}

// ---------------- fp32 -> bf16 casts ----------------
__global__ __launch_bounds__(256) void cast_kernel(
    const float* __restrict__ s0, const float* __restrict__ s1,
    const float* __restrict__ s2, const float* __restrict__ s3,
    ushort* __restrict__ d0, ushort* __restrict__ d1,
    ushort* __restrict__ d2, ushort* __restrict__ d3)
{
    const int seg = blockIdx.y;
    const float* src = seg == 0 ? s0 : seg == 1 ? s1 : seg == 2 ? s2 : s3;
    ushort* dst      = seg == 0 ? d0 : seg == 1 ? d1 : seg == 2 ? d2 : d3;
    const int n4 = (seg == 0 ? kB * kS * kD : kD * kD) / 4;
    for (int i = blockIdx.x * 256 + threadIdx.x; i < n4; i += gridDim.x * 256) {
        float4 v = *(const float4*)&src[(size_t)i * 4];
        short4v o;
        o[0] = (short)f2bf(v.x); o[1] = (short)f2bf(v.y);
        o[2] = (short)f2bf(v.z); o[3] = (short)f2bf(v.w);
        *(short4v*)&dst[(size_t)i * 4] = o;
    }
}

// ---------------- QKV projection + fused hedgehog feature map (R13) ----------------
__global__ __launch_bounds__(256) void qkv_mfma_kernel(
    const ushort* __restrict__ hb,
    const ushort* __restrict__ Wqb, const ushort* __restrict__ Wkb,
    const ushort* __restrict__ Wvb,
    const float* __restrict__ bq, const float* __restrict__ bk,
    const float* __restrict__ bv,
    const float* __restrict__ Wfq, const float* __restrict__ bfq,
    const float* __restrict__ Wfk, const float* __restrict__ bfk,
    ushort* __restrict__ qd, ushort* __restrict__ kd, ushort* __restrict__ vTd,
    ushort* __restrict__ fqd, ushort* __restrict__ fkd,
    float* __restrict__ part)
{
    const int which = blockIdx.z;
    const ushort* __restrict__ Wb  = which == 0 ? Wqb : which == 1 ? Wkb : Wvb;
    const float* __restrict__ bias = which == 0 ? bq : which == 1 ? bk : bv;

    const int m0 = blockIdx.x * 128;
    const int n0 = blockIdx.y * 64;
    const int t = threadIdx.x, lane = t & 63, w = t >> 6;
    const int g = lane >> 4, ln = lane & 15;

    __shared__ __align__(16) ushort As[128 * 64];
    __shared__ __align__(16) ushort Bs[64 * 64];
    __shared__ __align__(16) ushort Ws[64 * 64];
    __shared__ float zsum[4][128];

    if (which < 2) {
        const float* __restrict__ Wf = (which == 0) ? Wfq : Wfk;
        const int row = t >> 2, ce = (t & 3) * 16;
        ushort tmp[16];
        #pragma unroll
        for (int c = 0; c < 16; c += 4) {
            float4 u = *(const float4*)&Wf[(size_t)row * 64 + ce + c];
            tmp[c + 0] = f2bf(u.x); tmp[c + 1] = f2bf(u.y);
            tmp[c + 2] = f2bf(u.z); tmp[c + 3] = f2bf(u.w);
        }
        const int sw = (row & 7) << 4;
        *(uint4*)((char*)Ws + row * 128 + ((ce * 2) ^ sw)) = *(uint4*)&tmp[0];
        *(uint4*)((char*)Ws + row * 128 + ((ce * 2 + 16) ^ sw)) = *(uint4*)&tmp[8];
    }

    f32x4 acc[2][4];
    #pragma unroll
    for (int rs = 0; rs < 2; ++rs)
        #pragma unroll
        for (int nt = 0; nt < 4; ++nt) acc[rs][nt] = (f32x4){0.f, 0.f, 0.f, 0.f};

    for (int k0 = 0; k0 < kD; k0 += 64) {
        gstageA128(As, hb + (size_t)m0 * kD + k0, kD, w, lane);
        gstage64x64(Bs, Wb + (size_t)n0 * kD + k0, kD, w, lane);
        asm volatile("s_waitcnt vmcnt(0)" ::: "memory");
        __builtin_amdgcn_sched_barrier(0);
        __builtin_amdgcn_s_barrier();

        short8 a[2][2], b[4][2];
        #pragma unroll
        for (int rs = 0; rs < 2; ++rs) {
            const int row = 32 * w + 16 * rs + ln, sw = (row & 7) << 4;
            #pragma unroll
            for (int kc = 0; kc < 2; ++kc)
                a[rs][kc] = *(const short8*)((const char*)As + row * 128 + ((kc * 64 + g * 16) ^ sw));
        }
        #pragma unroll
        for (int nt = 0; nt < 4; ++nt) {
            const int rk = nt * 16 + ln, sw = (rk & 7) << 4;
            #pragma unroll
            for (int kc = 0; kc < 2; ++kc)
                b[nt][kc] = *(const short8*)((const char*)Bs + rk * 128 + ((kc * 64 + g * 16) ^ sw));
        }
        #pragma unroll
        for (int rs = 0; rs < 2; ++rs)
            #pragma unroll
            for (int nt = 0; nt < 4; ++nt)
                #pragma unroll
                for (int kc = 0; kc < 2; ++kc)
                    acc[rs][nt] = __builtin_amdgcn_mfma_f32_16x16x32_bf16(
                        a[rs][kc], b[nt][kc], acc[rs][nt], 0, 0, 0);
        asm volatile("s_waitcnt lgkmcnt(0)" ::: "memory");
        __builtin_amdgcn_sched_barrier(0);
        __builtin_amdgcn_s_barrier();
    }

    const int hh = n0 >> 6;
    float bvn[4];
    #pragma unroll
    for (int nt = 0; nt < 4; ++nt) bvn[nt] = bias[n0 + nt * 16 + ln];

    if (which < 2) {
        ushort* __restrict__ dst = (which == 0) ? qd : kd;
        #pragma unroll
        for (int rs = 0; rs < 2; ++rs)
            #pragma unroll
            for (int nt = 0; nt < 4; ++nt)
                #pragma unroll
                for (int r = 0; r < 4; ++r) {
                    const int m = m0 + 32 * w + 16 * rs + g * 4 + r;
                    const int b_ = m >> 11, s_ = m & (kS - 1);
                    dst[((size_t)(b_ * kH + hh) * kS + s_) * kHD + nt * 16 + ln] =
                        f2bf(acc[rs][nt][r] + bvn[nt]);
                }
    } else {
        #pragma unroll
        for (int rs = 0; rs < 2; ++rs)
            #pragma unroll
            for (int nt = 0; nt < 4; ++nt) {
                const int m = m0 + 32 * w + 16 * rs + g * 4;
                const int b_ = m >> 11, s_ = m & (kS - 1);
                const int d = nt * 16 + ln;
                short4v o;
                #pragma unroll
                for (int r = 0; r < 4; ++r) o[r] = (short)f2bf(acc[rs][nt][r] + bvn[nt]);
                *(short4v*)&vTd[((size_t)(b_ * kH + hh) * kHD + d) * kS + s_] = o;
            }
    }

    if (which < 2) {
        __syncthreads();
        #pragma unroll
        for (int rs = 0; rs < 2; ++rs)
            #pragma unroll
            for (int nt = 0; nt < 4; ++nt)
                #pragma unroll
                for (int r = 0; r < 4; ++r) {
                    const int bm = 32 * w + 16 * rs + g * 4 + r;
                    const int e = nt * 16 + ln;
                    *(ushort*)((char*)As + bm * 128 + ((2 * e) ^ ((bm & 7) << 4))) =
                        f2bf(acc[rs][nt][r] + bvn[nt]);
                }
        __syncthreads();

        short8 a2[2][2], b2[4][2];
        #pragma unroll
        for (int rs = 0; rs < 2; ++rs) {
            const int row = 32 * w + 16 * rs + ln, sw = (row & 7) << 4;
            #pragma unroll
            for (int kc = 0; kc < 2; ++kc)
                a2[rs][kc] = *(const short8*)((const char*)As + row * 128 + ((kc * 64 + g * 16) ^ sw));
        }
        #pragma unroll
        for (int nt = 0; nt < 4; ++nt) {
            const int rk = nt * 16 + ln, sw = (rk & 7) << 4;
            #pragma unroll
            for (int kc = 0; kc < 2; ++kc)
                b2[nt][kc] = *(const short8*)((const char*)Ws + rk * 128 + ((kc * 64 + g * 16) ^ sw));
        }
        f32x4 yac[2][4];
        #pragma unroll
        for (int rs = 0; rs < 2; ++rs)
            #pragma unroll
            for (int nt = 0; nt < 4; ++nt) {
                yac[rs][nt] = (f32x4){0.f, 0.f, 0.f, 0.f};
                #pragma unroll
                for (int kc = 0; kc < 2; ++kc)
                    yac[rs][nt] = __builtin_amdgcn_mfma_f32_16x16x32_bf16(
                        a2[rs][kc], b2[nt][kc], yac[rs][nt], 0, 0, 0);
            }

        const float* __restrict__ bf2p = (which == 0) ? bfq : bfk;
        float bfv[4];
        #pragma unroll
        for (int nt = 0; nt < 4; ++nt) bfv[nt] = bf2p[nt * 16 + ln];

        ushort* __restrict__ dstF = (which == 0) ? fqd : fkd;
        float csp[4] = {0.f, 0.f, 0.f, 0.f}, csm[4] = {0.f, 0.f, 0.f, 0.f};
        #pragma unroll
        for (int rs = 0; rs < 2; ++rs)
            #pragma unroll
            for (int nt = 0; nt < 4; ++nt)
                #pragma unroll
                for (int r = 0; r < 4; ++r) {
                    const int m = m0 + 32 * w + 16 * rs + g * 4 + r;
                    const int b_ = m >> 11, s_ = m & (kS - 1);
                    const float y = yac[rs][nt][r] + bfv[nt];
                    const ushort hp = f2bf(__expf(y));
                    const ushort hm = f2bf(__expf(-y));
                    const size_t base =
                        ((size_t)(b_ * kH + hh) * kS + s_) * kF + nt * 16 + ln;
                    dstF[base] = hp;
                    dstF[base + 64] = hm;
                    if (which == 1) { csp[nt] += bf2f(hp); csm[nt] += bf2f(hm); }
                }

        if (which == 1) {
            #pragma unroll
            for (int nt = 0; nt < 4; ++nt) {
                csp[nt] += __shfl_xor(csp[nt], 16); csp[nt] += __shfl_xor(csp[nt], 32);
                csm[nt] += __shfl_xor(csm[nt], 16); csm[nt] += __shfl_xor(csm[nt], 32);
            }
            if (g == 0) {
                #pragma unroll
                for (int nt = 0; nt < 4; ++nt) {
                    zsum[w][nt * 16 + ln]      = csp[nt];
                    zsum[w][64 + nt * 16 + ln] = csm[nt];
                }
            }
            __syncthreads();
            if (t < 128) {
                const float s = zsum[0][t] + zsum[1][t] + zsum[2][t] + zsum[3][t];
                const int b_ = m0 >> 11, gr = (m0 & (kS - 1)) >> 7;
                part[((size_t)((b_ * kH + hh) * 16 + gr)) * kF + t] = s;
            }
        }
    }
}

// ---------------- softmax attention: 8-wave, Ps aliased onto Qs (40 KB LDS) ----------------
__global__ __launch_bounds__(512) void true_attn_kernel(
    const ushort* __restrict__ q, const ushort* __restrict__ k,
    const ushort* __restrict__ vT,
    float* __restrict__ out0, float* __restrict__ out2)
{
    const int orig = blockIdx.y * 32 + blockIdx.x;        // 768 blocks
    const int swz  = (orig & 7) * 96 + (orig >> 3);
    const int bh = swz >> 5, m0 = (swz & 31) * 64;

    const int t = threadIdx.x, lane = t & 63, w = t >> 6;  // w in [0,8)
    const int g = lane >> 4, ln = lane & 15;
    const int wr = w & 3, wc = w >> 2;

    __shared__ __align__(16) ushort QPs[64 * 64];         // 8 KB: Q (pass1 hoist), then P
    __shared__ __align__(16) ushort KVs[4 * 64 * 64];     // 32 KB
    __shared__ float zl[8][16];

    const ushort* __restrict__ qb = q  + (size_t)bh * kS * kHD;
    const ushort* __restrict__ kb = k  + (size_t)bh * kS * kHD;
    const ushort* __restrict__ vb = vT + (size_t)bh * kHD * kS;

    {   // stage Q
        const int row = t >> 3, ce = (t & 7) * 8;
        uint4 u = *(const uint4*)(qb + (size_t)(m0 + row) * kHD + ce);
        *(uint4*)((char*)QPs + row * 128 + ((ce * 2) ^ ((row & 7) << 4))) = u;
    }
    __syncthreads();

    short8 aq[2];
    {
        const int row = 16 * wr + ln, sw = (row & 7) << 4;
        #pragma unroll
        for (int kc = 0; kc < 2; ++kc)
            aq[kc] = *(const short8*)((const char*)QPs + row * 128 + ((kc * 64 + g * 16) ^ sw));
    }

    // ---- pass 1: quad-buffered K, depth 2, one barrier/iter ----
    gstage8x64(KVs, kb, kHD, w, lane);
    gstage8x64(KVs + 4096, kb + (size_t)64 * kHD, kHD, w, lane);
    float zacc[4] = {0.f, 0.f, 0.f, 0.f};
    for (int tt = 0; tt < 32; ++tt) {
        if (tt + 2 < 32) {
            gstage8x64(KVs + ((tt + 2) & 3) * 4096,
                       kb + (size_t)(tt + 2) * 64 * kHD, kHD, w, lane);
            asm volatile("s_waitcnt vmcnt(2)" ::: "memory");
        } else if (tt == 30) {
            asm volatile("s_waitcnt vmcnt(1)" ::: "memory");
        } else {
            asm volatile("s_waitcnt vmcnt(0)" ::: "memory");
        }
        __builtin_amdgcn_sched_barrier(0);
        __builtin_amdgcn_s_barrier();
        const ushort* KsC = KVs + (tt & 3) * 4096;
        #pragma unroll
        for (int h2 = 0; h2 < 2; ++h2) {
            const int nt = 2 * wc + h2;
            f32x4 c = {0.f, 0.f, 0.f, 0.f};
            const int rk = nt * 16 + ln, sw = (rk & 7) << 4;
            #pragma unroll
            for (int kc = 0; kc < 2; ++kc) {
                short8 b = *(const short8*)((const char*)KsC + rk * 128 + ((kc * 64 + g * 16) ^ sw));
                c = __builtin_amdgcn_mfma_f32_16x16x32_bf16(aq[kc], b, c, 0, 0, 0);
            }
            #pragma unroll
            for (int r = 0; r < 4; ++r) zacc[r] += __expf(c[r] * 0.125f);
        }
    }
    #pragma unroll
    for (int r = 0; r < 4; ++r) {
        float z = zacc[r];
        z += __shfl_xor(z, 1); z += __shfl_xor(z, 2);
        z += __shfl_xor(z, 4); z += __shfl_xor(z, 8);
        zacc[r] = z;
    }
    if (ln == 0) {
        #pragma unroll
        for (int r = 0; r < 4; ++r) zl[w][g * 4 + r] = zacc[r];
    }
    __syncthreads();
    float invl[4];
    #pragma unroll
    for (int r = 0; r < 4; ++r)
        invl[r] = 1.f / (zl[wr][g * 4 + r] + zl[4 + wr][g * 4 + r]);

    // ---- pass 2: probs + PV; P tile reuses the Q LDS space ----
    f32x4 accv[2];
    accv[0] = (f32x4){0.f, 0.f, 0.f, 0.f};
    accv[1] = (f32x4){0.f, 0.f, 0.f, 0.f};

    gstage8x64(KVs, kb, kHD, w, lane);
    gstage8x64(KVs + 2 * 4096, vb, kS, w, lane);
    for (int tt = 0; tt < 32; ++tt) {
        const int cur = tt & 1;
        const int n0 = tt * 64;
        if (tt + 1 < 32) {
            gstage8x64(KVs + (cur ^ 1) * 4096,
                       kb + (size_t)(tt + 1) * 64 * kHD, kHD, w, lane);
            gstage8x64(KVs + (2 + (cur ^ 1)) * 4096,
                       vb + (tt + 1) * 64, kS, w, lane);
            asm volatile("s_waitcnt vmcnt(2)" ::: "memory");
        } else {
            asm volatile("s_waitcnt vmcnt(0)" ::: "memory");
        }
        __builtin_amdgcn_sched_barrier(0);
        __builtin_amdgcn_s_barrier();

        const ushort* KsC = KVs + cur * 4096;
        const ushort* VsC = KVs + (2 + cur) * 4096;
        #pragma unroll
        for (int h2 = 0; h2 < 2; ++h2) {
            const int nt = 2 * wc + h2;
            f32x4 c = {0.f, 0.f, 0.f, 0.f};
            const int rk = nt * 16 + ln, sw = (rk & 7) << 4;
            #pragma unroll
            for (int kc = 0; kc < 2; ++kc) {
                short8 b = *(const short8*)((const char*)KsC + rk * 128 + ((kc * 64 + g * 16) ^ sw));
                c = __builtin_amdgcn_mfma_f32_16x16x32_bf16(aq[kc], b, c, 0, 0, 0);
            }
            #pragma unroll
            for (int r = 0; r < 4; ++r) {
                const int prow = 16 * wr + g * 4 + r;
                const float p = __expf(c[r] * 0.125f) * invl[r];
                out2[((size_t)bh * kS + m0 + prow) * kS + n0 + nt * 16 + ln] = p;
                const int pb = prow * 128 + ((2 * (nt * 16 + ln)) ^ ((prow & 7) << 4));
                *(ushort*)((char*)QPs + pb) = f2bf(p);
            }
        }
        asm volatile("s_waitcnt lgkmcnt(0)" ::: "memory");
        __builtin_amdgcn_sched_barrier(0);
        __builtin_amdgcn_s_barrier();   // P rows shared across the wave pair

        const int rowp = 16 * wr + ln, swp = (rowp & 7) << 4;
        #pragma unroll
        for (int kc = 0; kc < 2; ++kc) {
            short8 pa = *(const short8*)((const char*)QPs + rowp * 128 + ((kc * 64 + g * 16) ^ swp));
            #pragma unroll
            for (int d2 = 0; d2 < 2; ++d2) {
                const int dt = 2 * wc + d2;
                const int rv = dt * 16 + ln, swv = (rv & 7) << 4;
                short8 bv = *(const short8*)((const char*)VsC + rv * 128 + ((kc * 64 + g * 16) ^ swv));
                accv[d2] = __builtin_amdgcn_mfma_f32_16x16x32_bf16(pa, bv, accv[d2], 0, 0, 0);
            }
        }
        __builtin_amdgcn_sched_barrier(0);
        __builtin_amdgcn_s_barrier();
    }

    const int b_ = bh / kH, h_ = bh % kH;
    #pragma unroll
    for (int d2 = 0; d2 < 2; ++d2)
        #pragma unroll
        for (int r = 0; r < 4; ++r) {
            const int prow = 16 * wr + g * 4 + r;
            const int dt = 2 * wc + d2;
            out0[((size_t)b_ * kS + m0 + prow) * kD + h_ * kHD + dt * 16 + ln] = accv[d2][r];
        }
}

// ---------------- hedgehog predicted attention: n-split, 32 KB LDS, 8 waves/SIMD ----------------
// 1536 blocks: idx -> bh = idx>>6, m0 = ((idx&63)>>1)*64, nhalf = idx&1.
__global__ __launch_bounds__(512) void pred_attn_kernel(
    const ushort* __restrict__ fq, const ushort* __restrict__ fk,
    const float* __restrict__ part, float* __restrict__ out1)
{
    const int orig = blockIdx.x;                          // 1536 blocks
    const int idx  = (orig & 7) * 192 + (orig >> 3);      // bijective XCD swizzle
    const int bh = idx >> 6, m0 = ((idx & 63) >> 1) * 64, nhalf = idx & 1;

    const int t = threadIdx.x, lane = t & 63, w = t >> 6;  // w in [0,8)
    const int g = lane >> 4, ln = lane & 15;
    const int wr = w & 3, wc = w >> 2;

    __shared__ __align__(16) ushort sbuf[2 * 64 * 128];    // 32 KB: Fq then Fk dbuf
    __shared__ float fsum[128];
    __shared__ float invz[64];

    const ushort* __restrict__ fqb = fq + (size_t)bh * kS * kF;
    const ushort* __restrict__ fkb = fk + (size_t)bh * kS * kF;

    {   // stage Fq into first 16 KB
        const int row = t >> 3, ce = (t & 7) * 16;
        const ushort* s = fqb + (size_t)(m0 + row) * kF + ce;
        const int sw = (row & 7) << 4;
        *(uint4*)((char*)sbuf + row * 256 + ((ce * 2) ^ sw)) = *(const uint4*)s;
        *(uint4*)((char*)sbuf + row * 256 + ((ce * 2 + 16) ^ sw)) = *(const uint4*)(s + 8);
    }
    if (t < 128) {
        float s = 0.f;
        #pragma unroll
        for (int gg = 0; gg < 16; ++gg) s += part[((size_t)bh * 16 + gg) * kF + t];
        fsum[t] = s;
    }
    __syncthreads();

    short8 a[4];
    {
        const int row = 16 * wr + ln, sw = (row & 7) << 4;
        #pragma unroll
        for (int kc = 0; kc < 4; ++kc)
            a[kc] = *(const short8*)((const char*)sbuf + row * 256 + ((kc * 64 + g * 16) ^ sw));
    }

    float den = 0.f;
    #pragma unroll
    for (int kc = 0; kc < 4; ++kc)
        #pragma unroll
        for (int j = 0; j < 8; ++j)
            den += bf2f((ushort)a[kc][j]) * fsum[kc * 32 + g * 8 + j];
    den += __shfl_xor(den, 16);
    den += __shfl_xor(den, 32);
    if (g == 0) invz[16 * wr + ln] = 1.f / den;
    __syncthreads();    // also: all waves done reading Fq -> sbuf reusable for Fk
    float invl[4];
    #pragma unroll
    for (int r = 0; r < 4; ++r) invl[r] = invz[16 * wr + g * 4 + r];

    const int t0 = nhalf * 16;                             // this block's 16 n-tiles
    gstage8x128(sbuf, fkb + (size_t)t0 * 64 * kF, w, lane);
    for (int tt = 0; tt < 16; ++tt) {
        const int cur = tt & 1;
        const int n0 = (t0 + tt) * 64;
        if (tt + 1 < 16) {
            gstage8x128(sbuf + (cur ^ 1) * 8192,
                        fkb + (size_t)(t0 + tt + 1) * 64 * kF, w, lane);
            asm volatile("s_waitcnt vmcnt(2)" ::: "memory");
        } else {
            asm volatile("s_waitcnt vmcnt(0)" ::: "memory");
        }
        __builtin_amdgcn_sched_barrier(0);
        __builtin_amdgcn_s_barrier();

        const ushort* FkC = sbuf + cur * 8192;
        #pragma unroll
        for (int h2 = 0; h2 < 2; ++h2) {
            const int nt = 2 * wc + h2;
            f32x4 c = {0.f, 0.f, 0.f, 0.f};
            const int rk = nt * 16 + ln, sw = (rk & 7) << 4;
            #pragma unroll
            for (int kc = 0; kc < 4; ++kc) {
                short8 b = *(const short8*)((const char*)FkC + rk * 256 + ((kc * 64 + g * 16) ^ sw));
                c = __builtin_amdgcn_mfma_f32_16x16x32_bf16(a[kc], b, c, 0, 0, 0);
            }
            #pragma unroll
            for (int r = 0; r < 4; ++r)
                out1[((size_t)bh * kS + m0 + 16 * wr + g * 4 + r) * kS + n0 + nt * 16 + ln] =
                    c[r] * invl[r];
        }
        __builtin_amdgcn_sched_barrier(0);
        __builtin_amdgcn_s_barrier();
    }
}

}  // namespace

extern "C" void kernel_launch(void* const* d_in, const int* in_sizes, int n_in,
                              void* d_out, int out_size, void* d_ws, size_t ws_size,
                              hipStream_t stream)
{
    (void)in_sizes; (void)n_in; (void)out_size; (void)ws_size;

    const float* hidden = (const float*)d_in[0];
    const float* Wq = (const float*)d_in[1];
    const float* bq = (const float*)d_in[2];
    const float* Wk = (const float*)d_in[3];
    const float* bk = (const float*)d_in[4];
    const float* Wv = (const float*)d_in[5];
    const float* bv = (const float*)d_in[6];
    const float* Wfq = (const float*)d_in[7];
    const float* bfq = (const float*)d_in[8];
    const float* Wfk = (const float*)d_in[9];
    const float* bfk = (const float*)d_in[10];

    float* out = (float*)d_out;
    float* out0 = out;                                   // outputs   [B,S,D]
    float* out1 = out0 + (size_t)kB * kS * kD;           // pred_attns[B,H,S,S]
    float* out2 = out1 + (size_t)kBH * kS * kS;          // true_attns[B,H,S,S]

    float* part = (float*)d_ws;                          // [kBH*16*kF]
    ushort* hb  = (ushort*)(part + (size_t)kBH * 16 * kF);   // hidden bf16
    ushort* Wqb = hb  + (size_t)kB * kS * kD;
    ushort* Wkb = Wqb + (size_t)kD * kD;
    ushort* Wvb = Wkb + (size_t)kD * kD;
    ushort* qw  = Wvb + (size_t)kD * kD;
    ushort* kw  = qw  + (size_t)kBH * kS * kHD;
    ushort* vTw = kw  + (size_t)kBH * kS * kHD;
    ushort* fqw = vTw + (size_t)kBH * kS * kHD;
    ushort* fkw = fqw + (size_t)kBH * kS * kF;

    cast_kernel<<<dim3(512, 4), 256, 0, stream>>>(
        hidden, Wq, Wk, Wv, hb, Wqb, Wkb, Wvb);
    qkv_mfma_kernel<<<dim3(kB * kS / 128, kD / 64, 3), 256, 0, stream>>>(
        hb, Wqb, Wkb, Wvb, bq, bk, bv,
        Wfq, bfq, Wfk, bfk,
        qw, kw, vTw, fqw, fkw, part);
    true_attn_kernel<<<dim3(kS / 64, kBH), 512, 0, stream>>>(qw, kw, vTw, out0, out2);
    pred_attn_kernel<<<dim3(2 * kS / 64 * kBH / 2 * 2), 512, 0, stream>>>(
        fqw, fkw, part, out1);
}